// Round 4
// baseline (4317.992 us; speedup 1.0000x reference)
//
#include <hip/hip_runtime.h>
#include <hip/hip_bf16.h>

// ---------------- model constants ----------------
#define TSEQ   4096
#define DIMM   1024
#define NHEADS 8
#define DH     128
#define NHASH  4
#define NBUCK  64
#define NCHUNK 256           // NHASH * NBUCK chunks of 64 sorted positions
#define BSZ    2
#define NBH    16            // BSZ * NHEADS
#define FFD    4096

typedef __attribute__((ext_vector_type(4))) float f32x4;
typedef __attribute__((ext_vector_type(8))) short s16x8;
typedef __attribute__((ext_vector_type(2))) double f64x2;

__device__ __forceinline__ unsigned short f2bf(float f) {
    union { float f; unsigned int u; } x; x.f = f;
    unsigned int r = x.u + 0x7FFFu + ((x.u >> 16) & 1u);   // RNE
    return (unsigned short)(r >> 16);
}

__device__ __forceinline__ void async16(const void* g, void* l) {
    __builtin_amdgcn_global_load_lds(
        (const __attribute__((address_space(1))) unsigned int*)g,
        (__attribute__((address_space(3))) unsigned int*)l, 16, 0, 0);
}

__device__ __forceinline__ float gelu_tanh(float x) {
    float x3 = x * x * x;
    float inner = 0.7978845608028654f * (x + 0.044715f * x3);
    return 0.5f * x * (1.0f + tanhf(inner));
}

// ---------------- init / zero / converts ----------------
__global__ void init_kernel(const float* __restrict__ x, float* __restrict__ X1,
                            float* __restrict__ X2, int n) {
    int i = blockIdx.x * blockDim.x + threadIdx.x;
    if (i < n) { float v = x[i]; X1[i] = v; X2[i] = v; }
}

__global__ void zero_kernel(float* __restrict__ p, int n) {
    int i = blockIdx.x * blockDim.x + threadIdx.x;
    if (i < n) p[i] = 0.f;
}

__global__ void initmw_kernel(float* __restrict__ M, float* __restrict__ W, int n) {
    int i = blockIdx.x * blockDim.x + threadIdx.x;
    if (i < n) { M[i] = -3.0e38f; W[i] = 0.f; }
}

// AOb = bf16(U / Wsum)
__global__ void div_kernel(const float* __restrict__ U, const float* __restrict__ Wst,
                           unsigned short* __restrict__ AOb, int n) {
    int i = blockIdx.x * blockDim.x + threadIdx.x;
    if (i < n) {
        int row = i >> 10, col = i & 1023;
        int b = row >> 12, t = row & 4095, head = col >> 7;
        float w = Wst[(size_t)(b * 8 + head) * TSEQ + t];
        AOb[i] = f2bf(U[i] / w);
    }
}

// convert + transpose: in[K x N] fp32 -> out[N x K] bf16
__global__ __launch_bounds__(256) void convT_kernel(const float* __restrict__ in,
                                                    unsigned short* __restrict__ out,
                                                    int K, int N) {
    __shared__ float tile[32][33];
    int n0 = blockIdx.x * 32, k0 = blockIdx.y * 32;
    int tx = threadIdx.x & 31, ty = threadIdx.x >> 5;
    #pragma unroll
    for (int r = 0; r < 4; r++)
        tile[ty + r * 8][tx] = in[(size_t)(k0 + ty + r * 8) * N + n0 + tx];
    __syncthreads();
    #pragma unroll
    for (int r = 0; r < 4; r++)
        out[(size_t)(n0 + ty + r * 8) * K + k0 + tx] = f2bf(tile[tx][ty + r * 8]);
}

// ---------------- layernorm -> bf16 out ----------------
__global__ __launch_bounds__(256) void ln_bf16_kernel(const float* __restrict__ in,
                                                      const float* __restrict__ g,
                                                      const float* __restrict__ bb,
                                                      unsigned short* __restrict__ out) {
    int row = blockIdx.x;
    int tid = threadIdx.x;
    const float* xr = in + (size_t)row * DIMM;
    float v[4];
    float s = 0.f, sq = 0.f;
    #pragma unroll
    for (int k = 0; k < 4; k++) { float t = xr[tid + 256 * k]; v[k] = t; s += t; sq += t * t; }
    __shared__ float rs[256], rq[256];
    rs[tid] = s; rq[tid] = sq; __syncthreads();
    for (int off = 128; off > 0; off >>= 1) {
        if (tid < off) { rs[tid] += rs[tid + off]; rq[tid] += rq[tid + off]; }
        __syncthreads();
    }
    float mu  = rs[0] * (1.f / DIMM);
    float var = rq[0] * (1.f / DIMM) - mu * mu;
    float rstd = rsqrtf(var + 1e-5f);
    unsigned short* orow = out + (size_t)row * DIMM;
    #pragma unroll
    for (int k = 0; k < 4; k++) {
        int c = tid + 256 * k;
        orow[c] = f2bf((v[k] - mu) * rstd * g[c] + bb[c]);
    }
}

// ---------------- bf16 MFMA GEMM: C = A @ B [+bias][gelu][+resid] ----------------
template<int OUT_BF16>
__global__ __launch_bounds__(256) void mgemm_kernel(const unsigned short* __restrict__ A,
                                                    const unsigned short* __restrict__ Bt,
                                                    const float* __restrict__ bias,
                                                    const float* __restrict__ resid,
                                                    void* __restrict__ Cv,
                                                    int M, int N, int K, int flags) {
    __shared__ __align__(16) unsigned short sA[128 * 32];
    __shared__ __align__(16) unsigned short sB[128 * 32];
    int tid = threadIdx.x;
    int wave = tid >> 6, lane = tid & 63;
    int n0 = blockIdx.x * 128, m0 = blockIdx.y * 128;
    int wr = (wave >> 1) * 64, wc = (wave & 1) * 64;
    f32x4 acc[4][4] = {};
    int c1 = tid, c2 = tid + 256;
    const unsigned short* gA1 = A + (size_t)(m0 + (c1 >> 2)) * K + (c1 & 3) * 8;
    const unsigned short* gA2 = A + (size_t)(m0 + (c2 >> 2)) * K + (c2 & 3) * 8;
    const unsigned short* gB1 = Bt + (size_t)(n0 + (c1 >> 2)) * K + (c1 & 3) * 8;
    const unsigned short* gB2 = Bt + (size_t)(n0 + (c2 >> 2)) * K + (c2 & 3) * 8;
    unsigned short* lA1 = sA + wave * 512;
    unsigned short* lA2 = sA + 2048 + wave * 512;
    unsigned short* lB1 = sB + wave * 512;
    unsigned short* lB2 = sB + 2048 + wave * 512;
    int qk8 = (lane >> 4) * 8;
    int r16 = lane & 15;
    for (int k0 = 0; k0 < K; k0 += 32) {
        __syncthreads();
        async16(gA1 + k0, lA1);
        async16(gA2 + k0, lA2);
        async16(gB1 + k0, lB1);
        async16(gB2 + k0, lB2);
        __syncthreads();
        s16x8 af[4], bf[4];
        #pragma unroll
        for (int i = 0; i < 4; i++) {
            af[i] = *(const s16x8*)&sA[(wr + i * 16 + r16) * 32 + qk8];
            bf[i] = *(const s16x8*)&sB[(wc + i * 16 + r16) * 32 + qk8];
        }
        #pragma unroll
        for (int mi = 0; mi < 4; mi++)
            #pragma unroll
            for (int ni = 0; ni < 4; ni++)
                acc[mi][ni] = __builtin_amdgcn_mfma_f32_16x16x32_bf16(af[mi], bf[ni], acc[mi][ni], 0, 0, 0);
    }
    #pragma unroll
    for (int mi = 0; mi < 4; mi++) {
        #pragma unroll
        for (int r = 0; r < 4; r++) {
            int row = m0 + wr + mi * 16 + (lane >> 4) * 4 + r;
            #pragma unroll
            for (int ni = 0; ni < 4; ni++) {
                int col = n0 + wc + ni * 16 + (lane & 15);
                float v = acc[mi][ni][r];
                if (flags & 1) v += bias[col];
                if (flags & 2) v = gelu_tanh(v);
                if (flags & 4) v += resid[(size_t)row * N + col];
                if (OUT_BF16) ((unsigned short*)Cv)[(size_t)row * N + col] = f2bf(v);
                else          ((float*)Cv)[(size_t)row * N + col] = v;
            }
        }
    }
}

// ---------------- bucketing path v7: LN64 + combined-projection fp64 GEMM ---------
// rotated = LN64(x) @ (Wqk_head @ rot_head). Per-output fp64 FMA chain (k0 tiles
// ascending, kk ascending, acc += a*b) is bit-identical to the verified v4/v6
// kernels. v7 removes LDS entirely: 1-wave blocks, lane j owns column n0+j
// (coalesced direct-global B reads, L2/L3-hot), A addresses are block-uniform
// (scalar-cache s_load -> SGPR broadcast operand of v_fma_f64). The previous
// version was LDS-pipe-bound (1 LDS pipe shared by 4 SIMDs, 2.2x oversubscribed,
// VALUBusy capped ~62%); this one has zero LDS traffic and zero barriers.

// LN in fp64 -> H64
__global__ __launch_bounds__(256) void ln64_kernel(const float* __restrict__ X,
                                                   const float* __restrict__ g,
                                                   const float* __restrict__ bb,
                                                   double* __restrict__ H64) {
    int row = blockIdx.x;
    int tid = threadIdx.x;
    const float* xr = X + (size_t)row * DIMM;
    __shared__ double rs[256], rq[256];
    double v[4];
    double s = 0.0, sq = 0.0;
    #pragma unroll
    for (int q = 0; q < 4; q++) {
        double t = (double)xr[tid + 256 * q];
        v[q] = t; s += t; sq += t * t;
    }
    rs[tid] = s; rq[tid] = sq; __syncthreads();
    for (int off = 128; off > 0; off >>= 1) {
        if (tid < off) { rs[tid] += rs[tid + off]; rq[tid] += rq[tid + off]; }
        __syncthreads();
    }
    double mu   = rs[0] * (1.0 / DIMM);
    double var  = rq[0] * (1.0 / DIMM) - mu * mu;
    double rstd = 1.0 / sqrt(var + 1e-5);
    double* orow = H64 + (size_t)row * DIMM;
    #pragma unroll
    for (int q = 0; q < 4; q++) {
        int c = tid + 256 * q;
        orow[c] = (v[q] - mu) * rstd * (double)g[c] + (double)bb[c];
    }
}

// R[k][hd*128 + cc] = sum_d Wqk[k][hd*128 + d] * rot[d][cc]   (fp64, serial d)
__global__ __launch_bounds__(256) void rcomb_kernel(const float* __restrict__ Wqk,
                                                    const float* __restrict__ rot,
                                                    double* __restrict__ R) {
    int k = blockIdx.x;                 // 0..1023
    int c0 = threadIdx.x * 4;           // 0..1020
    int hd = c0 >> 7;
    int cc = c0 & 127;
    const float* wrow = Wqk + (size_t)k * DIMM + hd * 128;
    double a0 = 0.0, a1 = 0.0, a2 = 0.0, a3 = 0.0;
    for (int d = 0; d < 128; d++) {
        double w = (double)wrow[d];
        f32x4 r4 = *(const f32x4*)&rot[d * 128 + cc];
        a0 += w * (double)r4.x; a1 += w * (double)r4.y;
        a2 += w * (double)r4.z; a3 += w * (double)r4.w;
    }
    double* orow = R + (size_t)k * DIMM + c0;
    orow[0] = a0; orow[1] = a1; orow[2] = a2; orow[3] = a3;
}

// LDS-free fp64 GEMM (8192x1024x1024) with fused per-(head,hash) argmax -> bucket.
// 1 wave per block: 16 rows x 64 cols; lane j = column n0+j.
#define RKS 16
__global__ __launch_bounds__(64) void rotgemm_kernel(const double* __restrict__ H64,
                                                     const double* __restrict__ R,
                                                     int* __restrict__ bucket) {
    int lane = threadIdx.x;            // 0..63
    int n0 = blockIdx.x * 64;
    int m0 = blockIdx.y * 16;
    double acc[16] = {};
    const double* gB = R + n0 + lane;

    // prefetch B strip for tile 0
    double b[RKS], bn[RKS];
    #pragma unroll
    for (int kk = 0; kk < RKS; kk++) b[kk] = gB[(size_t)kk * DIMM];

    #pragma unroll 1
    for (int k0 = 0; k0 < DIMM; k0 += RKS) {
        // issue next tile's B loads (overlap with compute below)
        if (k0 + RKS < DIMM) {
            #pragma unroll
            for (int kk = 0; kk < RKS; kk++)
                bn[kk] = gB[(size_t)(k0 + RKS + kk) * DIMM];
        }
        // compute: A strip per row is block-uniform -> scalar loads / SGPR operand
        #pragma unroll
        for (int r = 0; r < 16; r++) {
            const double* ar = H64 + (size_t)(m0 + r) * DIMM + k0;
            #pragma unroll
            for (int kk = 0; kk < RKS; kk++)
                acc[r] += ar[kk] * b[kk];
        }
        #pragma unroll
        for (int kk = 0; kk < RKS; kk++) b[kk] = bn[kk];
    }

    // ---- fused argmax over 64 candidates (+cols 0..31, -cols -> idx 32..63) ----
    // Lane group g = lane>>5 owns hash-group cols [n0+32g, n0+32g+32).
    // Per-lane candidates ascending idx: (+acc, lane&31), (-acc, 32+(lane&31));
    // strict > local, (val, min-idx) cross-lane over the 32-lane group
    // (xor offsets 1..16 preserve bit 5): exact first-max-wins.
    int l31 = lane & 31;
    int hd = n0 >> 7;
    int hh = ((n0 + (lane & 32)) >> 5) & 3;
    #pragma unroll
    for (int r = 0; r < 16; r++) {
        double best = acc[r]; int bidx = l31;
        double vn = -acc[r];
        if (vn > best) { best = vn; bidx = 32 + l31; }
        #pragma unroll
        for (int off = 1; off < 32; off <<= 1) {
            double ov = __shfl_xor(best, off, 64);
            int    oi = __shfl_xor(bidx, off, 64);
            if (ov > best || (ov == best && oi < bidx)) { best = ov; bidx = oi; }
        }
        if (l31 == 0) {
            int row = m0 + r;
            int b_ = row >> 12, t = row & 4095;
            bucket[(size_t)((b_ * 8 + hd) * NHASH + hh) * TSEQ + t] = bidx;
        }
    }
}

// ---------------- stable counting sort per (bh, hash round) ----------------
__global__ __launch_bounds__(64) void sort_kernel(const int* __restrict__ bucket,
                                                  int* __restrict__ st) {
    int h = blockIdx.x, bh = blockIdx.y;
    int tid = threadIdx.x;
    __shared__ int sbuck[TSEQ];
    __shared__ int cnt[NBUCK];
    cnt[tid] = 0;
    __syncthreads();
    const int* brow = bucket + (size_t)(bh * NHASH + h) * TSEQ;
    for (int t = tid; t < TSEQ; t += 64) {
        int bu = brow[t];
        sbuck[t] = bu;
        atomicAdd(&cnt[bu], 1);
    }
    __syncthreads();
    if (tid == 0) {
        int run = 0;
        for (int i = 0; i < NBUCK; i++) { int c = cnt[i]; cnt[i] = run; run += c; }
    }
    __syncthreads();
    int off = cnt[tid];
    int* strow = st + (size_t)bh * (NHASH * TSEQ) + h * TSEQ;
    for (int t = 0; t < TSEQ; t++) {
        if (sbuck[t] == tid) strow[off++] = t;
    }
}

// ---------------- per-token key inverse norms ----------------
__global__ __launch_bounds__(256) void norm_kernel(const float* __restrict__ QK,
                                                   float* __restrict__ invn) {
    int bh = blockIdx.y;
    int b = bh >> 3, head = bh & 7;
    int wave = threadIdx.x >> 6, lane = threadIdx.x & 63;
    int t = blockIdx.x * 4 + wave;
    const float* row = QK + (size_t)(b * TSEQ + t) * DIMM + head * DH;
    float v0 = row[lane], v1 = row[lane + 64];
    float s = v0 * v0 + v1 * v1;
    #pragma unroll
    for (int off = 32; off > 0; off >>= 1) s += __shfl_xor(s, off, 64);
    if (lane == 0) invn[bh * TSEQ + t] = rsqrtf(s + 1e-12f);
}

// ---------------- chunked LSH attention, single pass, online cross-round combine ----
__global__ __launch_bounds__(256) void attn_online_kernel(const float* __restrict__ QK,
                                                          const float* __restrict__ V,
                                                          const float* __restrict__ invn,
                                                          const int* __restrict__ st,
                                                          float* __restrict__ Mst,
                                                          float* __restrict__ Wst,
                                                          float* __restrict__ U,
                                                          int roundBase) {
    int c  = roundBase + blockIdx.x;   // global chunk id
    int bh = blockIdx.y;
    int b = bh >> 3, head = bh & 7;
    const float* QKb = QK + (size_t)b * TSEQ * DIMM + head * DH;
    const float* Vb  = V  + (size_t)b * TSEQ * DIMM + head * DH;
    const int* stb = st + (size_t)bh * (NHASH * TSEQ);
    int prev = (c + NCHUNK - 1) & (NCHUNK - 1);
    int tid = threadIdx.x;
    int tx = tid & 15, ty = tid >> 4;

    __shared__ float sdots[64][129];
    __shared__ float sstage[3264];
    __shared__ int   sbt[64];
    __shared__ int   sbkt[128];
    __shared__ float sinv[128];
    __shared__ float sa[64], sb[64];

    if (tid < 64) sbt[tid] = stb[c * 64 + tid];
    if (tid < 128) {
        int j = tid;
        int p = (j < 64) ? (c * 64 + j) : (prev * 64 + j - 64);
        int tk = stb[p];
        sbkt[j] = tk;
        sinv[j] = invn[bh * TSEQ + tk];
    }
    __syncthreads();

    // ---- dots = bq @ bk^T ----
    float acc[4][8] = {};
    float* sQ = sstage;
    float* sK = sstage + 64 * 17;
    for (int d0 = 0; d0 < DH; d0 += 16) {
        #pragma unroll
        for (int q = 0; q < 4; q++) {
            int idx = q * 256 + tid;
            int i = idx >> 4, dd = idx & 15;
            sQ[i * 17 + dd] = QKb[(size_t)sbt[i] * DIMM + d0 + dd];
        }
        #pragma unroll
        for (int q = 0; q < 8; q++) {
            int idx = q * 256 + tid;
            int j = idx >> 4, dd = idx & 15;
            sK[j * 17 + dd] = QKb[(size_t)sbkt[j] * DIMM + d0 + dd];
        }
        __syncthreads();
        #pragma unroll
        for (int dd = 0; dd < 16; dd++) {
            float a[4], bv[8];
            #pragma unroll
            for (int ri = 0; ri < 4; ri++) a[ri] = sQ[(ty * 4 + ri) * 17 + dd];
            #pragma unroll
            for (int ci = 0; ci < 8; ci++) bv[ci] = sK[(tx + 16 * ci) * 17 + dd];
            #pragma unroll
            for (int ri = 0; ri < 4; ri++)
                #pragma unroll
                for (int ci = 0; ci < 8; ci++)
                    acc[ri][ci] += a[ri] * bv[ci];
        }
        __syncthreads();
    }
    const float scale = 0.08838834764831845f;
    #pragma unroll
    for (int ri = 0; ri < 4; ri++) {
        int i = ty * 4 + ri;
        #pragma unroll
        for (int ci = 0; ci < 8; ci++) {
            int j = tx + 16 * ci;
            float v = acc[ri][ci] * sinv[j] * scale;
            if (sbt[i] == sbkt[j]) v -= 1e5f;
            sdots[i][j] = v;
        }
    }
    __syncthreads();

    // ---- row softmax + online merge factors ----
    if (tid < 64) {
        float m = -3.402823466e38f;
        for (int j = 0; j < 128; j++) m = fmaxf(m, sdots[tid][j]);
        float s = 0.f;
        for (int j = 0; j < 128; j++) s += expf(sdots[tid][j] - m);
        float inv = 1.f / s;
        for (int j = 0; j < 128; j++) sdots[tid][j] = expf(sdots[tid][j] - m) * inv;
        float lse = m + logf(s);
        int tok = sbt[tid];
        size_t mi = (size_t)bh * TSEQ + tok;
        float oldM = Mst[mi], oldW = Wst[mi];
        float newM = fmaxf(oldM, lse);
        float af = expf(oldM - newM);
        float bf = expf(lse - newM);
        Mst[mi] = newM;
        Wst[mi] = oldW * af + bf;
        sa[tid] = af; sb[tid] = bf;
    }
    __syncthreads();

    // ---- PV then U update: U = U*a + (P@V)*b ----
    float acc2[4][8] = {};
    float* sV = sstage;
    for (int j0 = 0; j0 < 128; j0 += 16) {
        #pragma unroll
        for (int q = 0; q < 8; q++) {
            int idx = q * 256 + tid;
            int jj = idx >> 7, d = idx & 127;
            sV[jj * 129 + d] = Vb[(size_t)sbkt[j0 + jj] * DIMM + d];
        }
        __syncthreads();
        #pragma unroll
        for (int jj = 0; jj < 16; jj++) {
            float a[4], vv[8];
            #pragma unroll
            for (int ri = 0; ri < 4; ri++) a[ri] = sdots[ty * 4 + ri][j0 + jj];
            #pragma unroll
            for (int ci = 0; ci < 8; ci++) vv[ci] = sV[jj * 129 + tx + 16 * ci];
            #pragma unroll
            for (int ri = 0; ri < 4; ri++)
                #pragma unroll
                for (int ci = 0; ci < 8; ci++)
                    acc2[ri][ci] += a[ri] * vv[ci];
        }
        __syncthreads();
    }
    #pragma unroll
    for (int ri = 0; ri < 4; ri++) {
        int i = ty * 4 + ri;
        float af = sa[i], bf = sb[i];
        float* urow = U + (size_t)(b * TSEQ + sbt[i]) * DIMM + head * DH;
        #pragma unroll
        for (int ci = 0; ci < 8; ci++) {
            int d = tx + 16 * ci;
            urow[d] = urow[d] * af + acc2[ri][ci] * bf;
        }
    }
}

// ---------------- final: out = 0.5*(X1+X2), fp32 ----------------
__global__ void final_kernel(const float* __restrict__ X1, const float* __restrict__ X2,
                             float* __restrict__ out, int n) {
    int i = blockIdx.x * blockDim.x + threadIdx.x;
    if (i < n) out[i] = 0.5f * (X1[i] + X2[i]);
}

extern "C" void kernel_launch(void* const* d_in, const int* in_sizes, int n_in,
                              void* d_out, int out_size, void* d_ws, size_t ws_size,
                              hipStream_t stream) {
    (void)in_sizes; (void)n_in; (void)out_size; (void)ws_size;
    const float* x    = (const float*)d_in[0];
    const float* ln1g = (const float*)d_in[2];
    const float* ln1b = (const float*)d_in[3];
    const float* Wqk  = (const float*)d_in[4];
    const float* Wv   = (const float*)d_in[5];
    const float* Wo   = (const float*)d_in[6];
    const float* bo   = (const float*)d_in[7];
    const float* ln2g = (const float*)d_in[8];
    const float* ln2b = (const float*)d_in[9];
    const float* W1   = (const float*)d_in[10];
    const float* b1   = (const float*)d_in[11];
    const float* W2   = (const float*)d_in[12];
    const float* b2   = (const float*)d_in[13];
    const float* rot  = (const float*)d_in[14];
    float* out = (float*)d_out;

    // ---- workspace layout (163.1 MB, same known-good footprint) ----
    char* ws = (char*)d_ws;
    const size_t SZ  = (size_t)BSZ * TSEQ * DIMM * sizeof(float);   // 32 MB
    const size_t HSZ = SZ / 2;                                      // 16 MB
    float* X1 = (float*)(ws + 0 * SZ);
    float* X2 = (float*)(ws + 1 * SZ);
    unsigned short* Hb  = (unsigned short*)(ws + 2 * SZ);           // LN out bf16
    unsigned short* Wb  = (unsigned short*)(ws + 2 * SZ + HSZ);     // weight bf16
    float* AO = (float*)(ws + 2 * SZ);                              // U accumulator fp32
    float* QK = (float*)(ws + 3 * SZ);
    unsigned short* AOb = (unsigned short*)(ws + 3 * SZ);
    unsigned short* Wob = (unsigned short*)(ws + 3 * SZ + HSZ);
    float* V = (float*)(ws + 4 * SZ);
    unsigned short* Hb2 = (unsigned short*)(ws + 4 * SZ);
    unsigned short* W1b = (unsigned short*)(ws + 4 * SZ + HSZ);
    unsigned short* W2b = (unsigned short*)(ws + 4 * SZ + HSZ + 8 * 1024 * 1024);
    unsigned short* G = (unsigned short*)(ws + 2 * SZ);             // FF hidden bf16 64MB
    // bucket-path scratch (live only at start of each layer, before Hb/QK/V):
    double* H64 = (double*)(ws + 2 * SZ);                           // 64 MB (2SZ..4SZ)
    double* Rc  = (double*)(ws + 4 * SZ);                           // 8 MB (inside V region)
    char* p = ws + 5 * SZ;
    float* Mst  = (float*)p; p += (size_t)NBH * TSEQ * sizeof(float);   // 256 KB
    float* Wst  = (float*)p; p += (size_t)NBH * TSEQ * sizeof(float);   // 256 KB
    float* invn = (float*)p; p += (size_t)NBH * TSEQ * sizeof(float);   // 256 KB
    int*   bucket = (int*)p; p += (size_t)NBH * NHASH * TSEQ * sizeof(int);
    int*   st     = (int*)p; p += (size_t)NBH * NHASH * TSEQ * sizeof(int);

    const int MROWS = BSZ * TSEQ;    // 8192
    const int NELEM = MROWS * DIMM;  // 8388608
    const int NMW = NBH * TSEQ;      // 65536

    init_kernel<<<(NELEM + 255) / 256, 256, 0, stream>>>(x, X1, X2, NELEM);

    for (int l = 0; l < 2; l++) {
        const float* wqk = Wqk + (size_t)l * DIMM * DIMM;
        const float* wv  = Wv  + (size_t)l * DIMM * DIMM;
        const float* wo  = Wo  + (size_t)l * DIMM * DIMM;
        const float* w1  = W1  + (size_t)l * DIMM * FFD;
        const float* w2  = W2  + (size_t)l * FFD * DIMM;
        const float* rotl = rot + (size_t)l * DH * NHASH * (NBUCK / 2);

        // ---- bucketing first (uses 2SZ..4SZ+8MB scratch while it's dead) ----
        ln64_kernel<<<MROWS, 256, 0, stream>>>(X2, ln1g + l * DIMM, ln1b + l * DIMM, H64);
        rcomb_kernel<<<DIMM, 256, 0, stream>>>(wqk, rotl, Rc);
        rotgemm_kernel<<<dim3(16, 512), 64, 0, stream>>>(H64, Rc, bucket);

        // ---- attention: a = LSHAttn(LN(x2)); y1 = x1 + a ----
        ln_bf16_kernel<<<MROWS, 256, 0, stream>>>(X2, ln1g + l * DIMM, ln1b + l * DIMM, Hb);
        convT_kernel<<<dim3(32, 32), 256, 0, stream>>>(wqk, Wb, DIMM, DIMM);
        mgemm_kernel<0><<<dim3(8, 64), 256, 0, stream>>>(Hb, Wb, nullptr, nullptr, QK,
                                                         MROWS, DIMM, DIMM, 0);
        convT_kernel<<<dim3(32, 32), 256, 0, stream>>>(wv, Wb, DIMM, DIMM);
        mgemm_kernel<0><<<dim3(8, 64), 256, 0, stream>>>(Hb, Wb, nullptr, nullptr, V,
                                                         MROWS, DIMM, DIMM, 0);
        sort_kernel<<<dim3(NHASH, NBH), 64, 0, stream>>>(bucket, st);
        norm_kernel<<<dim3(TSEQ / 4, NBH), 256, 0, stream>>>(QK, invn);
        initmw_kernel<<<(NMW + 255) / 256, 256, 0, stream>>>(Mst, Wst, NMW);
        zero_kernel<<<(NELEM + 255) / 256, 256, 0, stream>>>(AO, NELEM);
        for (int r = 0; r < NHASH; r++)
            attn_online_kernel<<<dim3(NBUCK, NBH), 256, 0, stream>>>(
                QK, V, invn, st, Mst, Wst, AO, r * NBUCK);
        div_kernel<<<(NELEM + 255) / 256, 256, 0, stream>>>(AO, Wst, AOb, NELEM);
        convT_kernel<<<dim3(32, 32), 256, 0, stream>>>(wo, Wob, DIMM, DIMM);
        mgemm_kernel<0><<<dim3(8, 64), 256, 0, stream>>>(AOb, Wob, bo + l * DIMM, X1, X1,
                                                         MROWS, DIMM, DIMM, 1 | 4);

        // ---- feed-forward: y2 = x2 + FF(LN(y1)) ----
        ln_bf16_kernel<<<MROWS, 256, 0, stream>>>(X1, ln2g + l * DIMM, ln2b + l * DIMM, Hb2);
        convT_kernel<<<dim3(128, 32), 256, 0, stream>>>(w1, W1b, DIMM, FFD);
        mgemm_kernel<1><<<dim3(32, 64), 256, 0, stream>>>(Hb2, W1b, b1 + l * FFD, nullptr, G,
                                                          MROWS, FFD, DIMM, 1 | 2);
        convT_kernel<<<dim3(32, 128), 256, 0, stream>>>(w2, W2b, FFD, DIMM);
        mgemm_kernel<0><<<dim3(8, 64), 256, 0, stream>>>(G, W2b, b2 + l * DIMM, X2, X2,
                                                         MROWS, DIMM, FFD, 1 | 4);
    }

    final_kernel<<<(NELEM + 255) / 256, 256, 0, stream>>>(X1, X2, out, NELEM);
}

// Round 5
// 3439.140 us; speedup vs baseline: 1.2555x; 1.2555x over previous
//
#include <hip/hip_runtime.h>
#include <hip/hip_bf16.h>

// ---------------- model constants ----------------
#define TSEQ   4096
#define DIMM   1024
#define NHEADS 8
#define DH     128
#define NHASH  4
#define NBUCK  64
#define NCHUNK 256           // NHASH * NBUCK chunks of 64 sorted positions
#define BSZ    2
#define NBH    16            // BSZ * NHEADS
#define FFD    4096

typedef __attribute__((ext_vector_type(4))) float f32x4;
typedef __attribute__((ext_vector_type(8))) short s16x8;
typedef __attribute__((ext_vector_type(2))) double f64x2;

__device__ __forceinline__ unsigned short f2bf(float f) {
    union { float f; unsigned int u; } x; x.f = f;
    unsigned int r = x.u + 0x7FFFu + ((x.u >> 16) & 1u);   // RNE
    return (unsigned short)(r >> 16);
}

__device__ __forceinline__ void async16(const void* g, void* l) {
    __builtin_amdgcn_global_load_lds(
        (const __attribute__((address_space(1))) unsigned int*)g,
        (__attribute__((address_space(3))) unsigned int*)l, 16, 0, 0);
}

__device__ __forceinline__ float gelu_tanh(float x) {
    float x3 = x * x * x;
    float inner = 0.7978845608028654f * (x + 0.044715f * x3);
    return 0.5f * x * (1.0f + tanhf(inner));
}

// ---------------- init / zero / converts ----------------
__global__ void init_kernel(const float* __restrict__ x, float* __restrict__ X1,
                            float* __restrict__ X2, int n) {
    int i = blockIdx.x * blockDim.x + threadIdx.x;
    if (i < n) { float v = x[i]; X1[i] = v; X2[i] = v; }
}

__global__ void zero_kernel(float* __restrict__ p, int n) {
    int i = blockIdx.x * blockDim.x + threadIdx.x;
    if (i < n) p[i] = 0.f;
}

__global__ void initmw_kernel(float* __restrict__ M, float* __restrict__ W, int n) {
    int i = blockIdx.x * blockDim.x + threadIdx.x;
    if (i < n) { M[i] = -3.0e38f; W[i] = 0.f; }
}

// AOb = bf16(U / Wsum)
__global__ void div_kernel(const float* __restrict__ U, const float* __restrict__ Wst,
                           unsigned short* __restrict__ AOb, int n) {
    int i = blockIdx.x * blockDim.x + threadIdx.x;
    if (i < n) {
        int row = i >> 10, col = i & 1023;
        int b = row >> 12, t = row & 4095, head = col >> 7;
        float w = Wst[(size_t)(b * 8 + head) * TSEQ + t];
        AOb[i] = f2bf(U[i] / w);
    }
}

// convert + transpose: in[K x N] fp32 -> out[N x K] bf16
__global__ __launch_bounds__(256) void convT_kernel(const float* __restrict__ in,
                                                    unsigned short* __restrict__ out,
                                                    int K, int N) {
    __shared__ float tile[32][33];
    int n0 = blockIdx.x * 32, k0 = blockIdx.y * 32;
    int tx = threadIdx.x & 31, ty = threadIdx.x >> 5;
    #pragma unroll
    for (int r = 0; r < 4; r++)
        tile[ty + r * 8][tx] = in[(size_t)(k0 + ty + r * 8) * N + n0 + tx];
    __syncthreads();
    #pragma unroll
    for (int r = 0; r < 4; r++)
        out[(size_t)(n0 + ty + r * 8) * K + k0 + tx] = f2bf(tile[tx][ty + r * 8]);
}

// ---------------- layernorm -> bf16 out ----------------
__global__ __launch_bounds__(256) void ln_bf16_kernel(const float* __restrict__ in,
                                                      const float* __restrict__ g,
                                                      const float* __restrict__ bb,
                                                      unsigned short* __restrict__ out) {
    int row = blockIdx.x;
    int tid = threadIdx.x;
    const float* xr = in + (size_t)row * DIMM;
    float v[4];
    float s = 0.f, sq = 0.f;
    #pragma unroll
    for (int k = 0; k < 4; k++) { float t = xr[tid + 256 * k]; v[k] = t; s += t; sq += t * t; }
    __shared__ float rs[256], rq[256];
    rs[tid] = s; rq[tid] = sq; __syncthreads();
    for (int off = 128; off > 0; off >>= 1) {
        if (tid < off) { rs[tid] += rs[tid + off]; rq[tid] += rq[tid + off]; }
        __syncthreads();
    }
    float mu  = rs[0] * (1.f / DIMM);
    float var = rq[0] * (1.f / DIMM) - mu * mu;
    float rstd = rsqrtf(var + 1e-5f);
    unsigned short* orow = out + (size_t)row * DIMM;
    #pragma unroll
    for (int k = 0; k < 4; k++) {
        int c = tid + 256 * k;
        orow[c] = f2bf((v[k] - mu) * rstd * g[c] + bb[c]);
    }
}

// ---------------- bf16 MFMA GEMM: C = A @ B [+bias][gelu][+resid] ----------------
template<int OUT_BF16>
__global__ __launch_bounds__(256) void mgemm_kernel(const unsigned short* __restrict__ A,
                                                    const unsigned short* __restrict__ Bt,
                                                    const float* __restrict__ bias,
                                                    const float* __restrict__ resid,
                                                    void* __restrict__ Cv,
                                                    int M, int N, int K, int flags) {
    __shared__ __align__(16) unsigned short sA[128 * 32];
    __shared__ __align__(16) unsigned short sB[128 * 32];
    int tid = threadIdx.x;
    int wave = tid >> 6, lane = tid & 63;
    int n0 = blockIdx.x * 128, m0 = blockIdx.y * 128;
    int wr = (wave >> 1) * 64, wc = (wave & 1) * 64;
    f32x4 acc[4][4] = {};
    int c1 = tid, c2 = tid + 256;
    const unsigned short* gA1 = A + (size_t)(m0 + (c1 >> 2)) * K + (c1 & 3) * 8;
    const unsigned short* gA2 = A + (size_t)(m0 + (c2 >> 2)) * K + (c2 & 3) * 8;
    const unsigned short* gB1 = Bt + (size_t)(n0 + (c1 >> 2)) * K + (c1 & 3) * 8;
    const unsigned short* gB2 = Bt + (size_t)(n0 + (c2 >> 2)) * K + (c2 & 3) * 8;
    unsigned short* lA1 = sA + wave * 512;
    unsigned short* lA2 = sA + 2048 + wave * 512;
    unsigned short* lB1 = sB + wave * 512;
    unsigned short* lB2 = sB + 2048 + wave * 512;
    int qk8 = (lane >> 4) * 8;
    int r16 = lane & 15;
    for (int k0 = 0; k0 < K; k0 += 32) {
        __syncthreads();
        async16(gA1 + k0, lA1);
        async16(gA2 + k0, lA2);
        async16(gB1 + k0, lB1);
        async16(gB2 + k0, lB2);
        __syncthreads();
        s16x8 af[4], bf[4];
        #pragma unroll
        for (int i = 0; i < 4; i++) {
            af[i] = *(const s16x8*)&sA[(wr + i * 16 + r16) * 32 + qk8];
            bf[i] = *(const s16x8*)&sB[(wc + i * 16 + r16) * 32 + qk8];
        }
        #pragma unroll
        for (int mi = 0; mi < 4; mi++)
            #pragma unroll
            for (int ni = 0; ni < 4; ni++)
                acc[mi][ni] = __builtin_amdgcn_mfma_f32_16x16x32_bf16(af[mi], bf[ni], acc[mi][ni], 0, 0, 0);
    }
    #pragma unroll
    for (int mi = 0; mi < 4; mi++) {
        #pragma unroll
        for (int r = 0; r < 4; r++) {
            int row = m0 + wr + mi * 16 + (lane >> 4) * 4 + r;
            #pragma unroll
            for (int ni = 0; ni < 4; ni++) {
                int col = n0 + wc + ni * 16 + (lane & 15);
                float v = acc[mi][ni][r];
                if (flags & 1) v += bias[col];
                if (flags & 2) v = gelu_tanh(v);
                if (flags & 4) v += resid[(size_t)row * N + col];
                if (OUT_BF16) ((unsigned short*)Cv)[(size_t)row * N + col] = f2bf(v);
                else          ((float*)Cv)[(size_t)row * N + col] = v;
            }
        }
    }
}

// ---------------- bucketing path v8: LN64 + combined-projection fp64 GEMM ---------
// rotated = LN64(x) @ (Wqk_head @ rot_head). Per-output fp64 FMA chain is
// k = 0..1023 strictly ascending with a single acc += a*b chain -> bit-identical
// per-output results to the verified v4/v6 kernels (K-tile size change does not
// reorder a serial per-output chain). v8 retiles v6 from 8x4 to 8x8 per thread
// (128x128 block tile, one head per block) to halve DS-instructions per FMA:
// v6 was LDS-instruction-throughput-bound (8 ds_reads per 128 VALU-cy, 4 waves
// sharing one LDS pipe -> VALUBusy capped ~62%).

// LN in fp64 -> H64
__global__ __launch_bounds__(256) void ln64_kernel(const float* __restrict__ X,
                                                   const float* __restrict__ g,
                                                   const float* __restrict__ bb,
                                                   double* __restrict__ H64) {
    int row = blockIdx.x;
    int tid = threadIdx.x;
    const float* xr = X + (size_t)row * DIMM;
    __shared__ double rs[256], rq[256];
    double v[4];
    double s = 0.0, sq = 0.0;
    #pragma unroll
    for (int q = 0; q < 4; q++) {
        double t = (double)xr[tid + 256 * q];
        v[q] = t; s += t; sq += t * t;
    }
    rs[tid] = s; rq[tid] = sq; __syncthreads();
    for (int off = 128; off > 0; off >>= 1) {
        if (tid < off) { rs[tid] += rs[tid + off]; rq[tid] += rq[tid + off]; }
        __syncthreads();
    }
    double mu   = rs[0] * (1.0 / DIMM);
    double var  = rq[0] * (1.0 / DIMM) - mu * mu;
    double rstd = 1.0 / sqrt(var + 1e-5);
    double* orow = H64 + (size_t)row * DIMM;
    #pragma unroll
    for (int q = 0; q < 4; q++) {
        int c = tid + 256 * q;
        orow[c] = (v[q] - mu) * rstd * (double)g[c] + (double)bb[c];
    }
}

// R[k][hd*128 + cc] = sum_d Wqk[k][hd*128 + d] * rot[d][cc]   (fp64, serial d)
__global__ __launch_bounds__(256) void rcomb_kernel(const float* __restrict__ Wqk,
                                                    const float* __restrict__ rot,
                                                    double* __restrict__ R) {
    int k = blockIdx.x;                 // 0..1023
    int c0 = threadIdx.x * 4;           // 0..1020
    int hd = c0 >> 7;
    int cc = c0 & 127;
    const float* wrow = Wqk + (size_t)k * DIMM + hd * 128;
    double a0 = 0.0, a1 = 0.0, a2 = 0.0, a3 = 0.0;
    for (int d = 0; d < 128; d++) {
        double w = (double)wrow[d];
        f32x4 r4 = *(const f32x4*)&rot[d * 128 + cc];
        a0 += w * (double)r4.x; a1 += w * (double)r4.y;
        a2 += w * (double)r4.z; a3 += w * (double)r4.w;
    }
    double* orow = R + (size_t)k * DIMM + c0;
    orow[0] = a0; orow[1] = a1; orow[2] = a2; orow[3] = a3;
}

// Tiled fp64 GEMM (8192x1024x1024) with fused per-(head,hash) argmax -> bucket.
// Block tile 128x128 (one head), 256 threads as 16x16, 8x8 fp64 acc/thread,
// K-step 8, register prefetch of next tile. Thread (tx,ty): rows ty*8+r,
// cols tx+16c.
#define RKS 8
__global__ __launch_bounds__(256, 2) void rotgemm_kernel(const double* __restrict__ H64,
                                                         const double* __restrict__ R,
                                                         int* __restrict__ bucket) {
    __shared__ double sA[RKS][130];   // [k][m], pitch 130 (1040B rows)
    __shared__ double sB[RKS][130];   // [k][n]
    int tid = threadIdx.x;
    int tx = tid & 15, ty = tid >> 4;
    int n0 = blockIdx.x * 128, m0 = blockIdx.y * 128;
    double acc[8][8] = {};            // [r][c]: row = ty*8+r, col = tx + 16*c

    int arow = tid >> 1, ak = (tid & 1) * 4;           // A stage: 4 fp64 / thread
    const double* gA = H64 + (size_t)(m0 + arow) * DIMM + ak;
    int bkk = tid >> 5, bn = (tid & 31) * 4;           // B stage: 4 fp64 / thread
    const double* gB = R + (size_t)bkk * DIMM + n0 + bn;

    // prefetch tile 0 into registers
    f64x2 a2[2], b2[2];
    a2[0] = *(const f64x2*)(gA);
    a2[1] = *(const f64x2*)(gA + 2);
    b2[0] = *(const f64x2*)(gB);
    b2[1] = *(const f64x2*)(gB + 2);

    for (int k0 = 0; k0 < DIMM; k0 += RKS) {
        __syncthreads();
        sA[ak + 0][arow] = a2[0].x;
        sA[ak + 1][arow] = a2[0].y;
        sA[ak + 2][arow] = a2[1].x;
        sA[ak + 3][arow] = a2[1].y;
        *(f64x2*)&sB[bkk][bn]     = b2[0];
        *(f64x2*)&sB[bkk][bn + 2] = b2[1];
        __syncthreads();
        // prefetch next tile (overlaps the compute phase below)
        if (k0 + RKS < DIMM) {
            const double* pa = gA + k0 + RKS;
            a2[0] = *(const f64x2*)(pa);
            a2[1] = *(const f64x2*)(pa + 2);
            const double* pb = gB + (size_t)(k0 + RKS) * DIMM;
            b2[0] = *(const f64x2*)(pb);
            b2[1] = *(const f64x2*)(pb + 2);
        }
        #pragma unroll
        for (int kk = 0; kk < RKS; kk++) {
            double a_[8], b_[8];
            #pragma unroll
            for (int u = 0; u < 4; u++) {
                f64x2 t = *(const f64x2*)&sA[kk][ty * 8 + 2 * u];
                a_[2 * u] = t.x; a_[2 * u + 1] = t.y;
            }
            #pragma unroll
            for (int c = 0; c < 8; c++) b_[c] = sB[kk][tx + 16 * c];
            #pragma unroll
            for (int r = 0; r < 8; r++)
                #pragma unroll
                for (int c = 0; c < 8; c++)
                    acc[r][c] += a_[r] * b_[c];
        }
    }

    // ---- fused argmax over 64 candidates (+cols 0..31, -cols -> idx 32..63) ----
    // Block covers one head (128 cols = 4 hash groups g). Group g = thread's
    // c in {2g, 2g+1}: candidate idx tx (c=2g), tx+16 (c=2g+1), 32+tx, 48+tx —
    // ascending-idx local scan with strict >, then (val, min-idx) reduce over
    // the 16-lane tx-group (xor 1,2,4,8 stay within group): exact first-max-wins.
    int hd = n0 >> 7;
    #pragma unroll
    for (int g = 0; g < 4; g++) {
        #pragma unroll
        for (int r = 0; r < 8; r++) {
            double best = acc[r][2 * g]; int bidx = tx;
            double v1 = acc[r][2 * g + 1];
            if (v1 > best) { best = v1; bidx = tx + 16; }
            double v2 = -acc[r][2 * g];
            if (v2 > best) { best = v2; bidx = 32 + tx; }
            double v3 = -acc[r][2 * g + 1];
            if (v3 > best) { best = v3; bidx = 48 + tx; }
            #pragma unroll
            for (int off = 1; off < 16; off <<= 1) {
                double ov = __shfl_xor(best, off, 64);
                int    oi = __shfl_xor(bidx, off, 64);
                if (ov > best || (ov == best && oi < bidx)) { best = ov; bidx = oi; }
            }
            if (tx == 0) {
                int row = m0 + ty * 8 + r;
                int b_ = row >> 12, t = row & 4095;
                bucket[(size_t)((b_ * 8 + hd) * NHASH + g) * TSEQ + t] = bidx;
            }
        }
    }
}

// ---------------- stable counting sort per (bh, hash round) ----------------
__global__ __launch_bounds__(64) void sort_kernel(const int* __restrict__ bucket,
                                                  int* __restrict__ st) {
    int h = blockIdx.x, bh = blockIdx.y;
    int tid = threadIdx.x;
    __shared__ int sbuck[TSEQ];
    __shared__ int cnt[NBUCK];
    cnt[tid] = 0;
    __syncthreads();
    const int* brow = bucket + (size_t)(bh * NHASH + h) * TSEQ;
    for (int t = tid; t < TSEQ; t += 64) {
        int bu = brow[t];
        sbuck[t] = bu;
        atomicAdd(&cnt[bu], 1);
    }
    __syncthreads();
    if (tid == 0) {
        int run = 0;
        for (int i = 0; i < NBUCK; i++) { int c = cnt[i]; cnt[i] = run; run += c; }
    }
    __syncthreads();
    int off = cnt[tid];
    int* strow = st + (size_t)bh * (NHASH * TSEQ) + h * TSEQ;
    for (int t = 0; t < TSEQ; t++) {
        if (sbuck[t] == tid) strow[off++] = t;
    }
}

// ---------------- per-token key inverse norms ----------------
__global__ __launch_bounds__(256) void norm_kernel(const float* __restrict__ QK,
                                                   float* __restrict__ invn) {
    int bh = blockIdx.y;
    int b = bh >> 3, head = bh & 7;
    int wave = threadIdx.x >> 6, lane = threadIdx.x & 63;
    int t = blockIdx.x * 4 + wave;
    const float* row = QK + (size_t)(b * TSEQ + t) * DIMM + head * DH;
    float v0 = row[lane], v1 = row[lane + 64];
    float s = v0 * v0 + v1 * v1;
    #pragma unroll
    for (int off = 32; off > 0; off >>= 1) s += __shfl_xor(s, off, 64);
    if (lane == 0) invn[bh * TSEQ + t] = rsqrtf(s + 1e-12f);
}

// ---------------- chunked LSH attention, single pass, online cross-round combine ----
__global__ __launch_bounds__(256) void attn_online_kernel(const float* __restrict__ QK,
                                                          const float* __restrict__ V,
                                                          const float* __restrict__ invn,
                                                          const int* __restrict__ st,
                                                          float* __restrict__ Mst,
                                                          float* __restrict__ Wst,
                                                          float* __restrict__ U,
                                                          int roundBase) {
    int c  = roundBase + blockIdx.x;   // global chunk id
    int bh = blockIdx.y;
    int b = bh >> 3, head = bh & 7;
    const float* QKb = QK + (size_t)b * TSEQ * DIMM + head * DH;
    const float* Vb  = V  + (size_t)b * TSEQ * DIMM + head * DH;
    const int* stb = st + (size_t)bh * (NHASH * TSEQ);
    int prev = (c + NCHUNK - 1) & (NCHUNK - 1);
    int tid = threadIdx.x;
    int tx = tid & 15, ty = tid >> 4;

    __shared__ float sdots[64][129];
    __shared__ float sstage[3264];
    __shared__ int   sbt[64];
    __shared__ int   sbkt[128];
    __shared__ float sinv[128];
    __shared__ float sa[64], sb[64];

    if (tid < 64) sbt[tid] = stb[c * 64 + tid];
    if (tid < 128) {
        int j = tid;
        int p = (j < 64) ? (c * 64 + j) : (prev * 64 + j - 64);
        int tk = stb[p];
        sbkt[j] = tk;
        sinv[j] = invn[bh * TSEQ + tk];
    }
    __syncthreads();

    // ---- dots = bq @ bk^T ----
    float acc[4][8] = {};
    float* sQ = sstage;
    float* sK = sstage + 64 * 17;
    for (int d0 = 0; d0 < DH; d0 += 16) {
        #pragma unroll
        for (int q = 0; q < 4; q++) {
            int idx = q * 256 + tid;
            int i = idx >> 4, dd = idx & 15;
            sQ[i * 17 + dd] = QKb[(size_t)sbt[i] * DIMM + d0 + dd];
        }
        #pragma unroll
        for (int q = 0; q < 8; q++) {
            int idx = q * 256 + tid;
            int j = idx >> 4, dd = idx & 15;
            sK[j * 17 + dd] = QKb[(size_t)sbkt[j] * DIMM + d0 + dd];
        }
        __syncthreads();
        #pragma unroll
        for (int dd = 0; dd < 16; dd++) {
            float a[4], bv[8];
            #pragma unroll
            for (int ri = 0; ri < 4; ri++) a[ri] = sQ[(ty * 4 + ri) * 17 + dd];
            #pragma unroll
            for (int ci = 0; ci < 8; ci++) bv[ci] = sK[(tx + 16 * ci) * 17 + dd];
            #pragma unroll
            for (int ri = 0; ri < 4; ri++)
                #pragma unroll
                for (int ci = 0; ci < 8; ci++)
                    acc[ri][ci] += a[ri] * bv[ci];
        }
        __syncthreads();
    }
    const float scale = 0.08838834764831845f;
    #pragma unroll
    for (int ri = 0; ri < 4; ri++) {
        int i = ty * 4 + ri;
        #pragma unroll
        for (int ci = 0; ci < 8; ci++) {
            int j = tx + 16 * ci;
            float v = acc[ri][ci] * sinv[j] * scale;
            if (sbt[i] == sbkt[j]) v -= 1e5f;
            sdots[i][j] = v;
        }
    }
    __syncthreads();

    // ---- row softmax + online merge factors ----
    if (tid < 64) {
        float m = -3.402823466e38f;
        for (int j = 0; j < 128; j++) m = fmaxf(m, sdots[tid][j]);
        float s = 0.f;
        for (int j = 0; j < 128; j++) s += expf(sdots[tid][j] - m);
        float inv = 1.f / s;
        for (int j = 0; j < 128; j++) sdots[tid][j] = expf(sdots[tid][j] - m) * inv;
        float lse = m + logf(s);
        int tok = sbt[tid];
        size_t mi = (size_t)bh * TSEQ + tok;
        float oldM = Mst[mi], oldW = Wst[mi];
        float newM = fmaxf(oldM, lse);
        float af = expf(oldM - newM);
        float bf = expf(lse - newM);
        Mst[mi] = newM;
        Wst[mi] = oldW * af + bf;
        sa[tid] = af; sb[tid] = bf;
    }
    __syncthreads();

    // ---- PV then U update: U = U*a + (P@V)*b ----
    float acc2[4][8] = {};
    float* sV = sstage;
    for (int j0 = 0; j0 < 128; j0 += 16) {
        #pragma unroll
        for (int q = 0; q < 8; q++) {
            int idx = q * 256 + tid;
            int jj = idx >> 7, d = idx & 127;
            sV[jj * 129 + d] = Vb[(size_t)sbkt[j0 + jj] * DIMM + d];
        }
        __syncthreads();
        #pragma unroll
        for (int jj = 0; jj < 16; jj++) {
            float a[4], vv[8];
            #pragma unroll
            for (int ri = 0; ri < 4; ri++) a[ri] = sdots[ty * 4 + ri][j0 + jj];
            #pragma unroll
            for (int ci = 0; ci < 8; ci++) vv[ci] = sV[jj * 129 + tx + 16 * ci];
            #pragma unroll
            for (int ri = 0; ri < 4; ri++)
                #pragma unroll
                for (int ci = 0; ci < 8; ci++)
                    acc2[ri][ci] += a[ri] * vv[ci];
        }
        __syncthreads();
    }
    #pragma unroll
    for (int ri = 0; ri < 4; ri++) {
        int i = ty * 4 + ri;
        float af = sa[i], bf = sb[i];
        float* urow = U + (size_t)(b * TSEQ + sbt[i]) * DIMM + head * DH;
        #pragma unroll
        for (int ci = 0; ci < 8; ci++) {
            int d = tx + 16 * ci;
            urow[d] = urow[d] * af + acc2[ri][ci] * bf;
        }
    }
}

// ---------------- final: out = 0.5*(X1+X2), fp32 ----------------
__global__ void final_kernel(const float* __restrict__ X1, const float* __restrict__ X2,
                             float* __restrict__ out, int n) {
    int i = blockIdx.x * blockDim.x + threadIdx.x;
    if (i < n) out[i] = 0.5f * (X1[i] + X2[i]);
}

extern "C" void kernel_launch(void* const* d_in, const int* in_sizes, int n_in,
                              void* d_out, int out_size, void* d_ws, size_t ws_size,
                              hipStream_t stream) {
    (void)in_sizes; (void)n_in; (void)out_size; (void)ws_size;
    const float* x    = (const float*)d_in[0];
    const float* ln1g = (const float*)d_in[2];
    const float* ln1b = (const float*)d_in[3];
    const float* Wqk  = (const float*)d_in[4];
    const float* Wv   = (const float*)d_in[5];
    const float* Wo   = (const float*)d_in[6];
    const float* bo   = (const float*)d_in[7];
    const float* ln2g = (const float*)d_in[8];
    const float* ln2b = (const float*)d_in[9];
    const float* W1   = (const float*)d_in[10];
    const float* b1   = (const float*)d_in[11];
    const float* W2   = (const float*)d_in[12];
    const float* b2   = (const float*)d_in[13];
    const float* rot  = (const float*)d_in[14];
    float* out = (float*)d_out;

    // ---- workspace layout (163.1 MB, same known-good footprint) ----
    char* ws = (char*)d_ws;
    const size_t SZ  = (size_t)BSZ * TSEQ * DIMM * sizeof(float);   // 32 MB
    const size_t HSZ = SZ / 2;                                      // 16 MB
    float* X1 = (float*)(ws + 0 * SZ);
    float* X2 = (float*)(ws + 1 * SZ);
    unsigned short* Hb  = (unsigned short*)(ws + 2 * SZ);           // LN out bf16
    unsigned short* Wb  = (unsigned short*)(ws + 2 * SZ + HSZ);     // weight bf16
    float* AO = (float*)(ws + 2 * SZ);                              // U accumulator fp32
    float* QK = (float*)(ws + 3 * SZ);
    unsigned short* AOb = (unsigned short*)(ws + 3 * SZ);
    unsigned short* Wob = (unsigned short*)(ws + 3 * SZ + HSZ);
    float* V = (float*)(ws + 4 * SZ);
    unsigned short* Hb2 = (unsigned short*)(ws + 4 * SZ);
    unsigned short* W1b = (unsigned short*)(ws + 4 * SZ + HSZ);
    unsigned short* W2b = (unsigned short*)(ws + 4 * SZ + HSZ + 8 * 1024 * 1024);
    unsigned short* G = (unsigned short*)(ws + 2 * SZ);             // FF hidden bf16 64MB
    // bucket-path scratch (live only at start of each layer, before Hb/QK/V):
    double* H64 = (double*)(ws + 2 * SZ);                           // 64 MB (2SZ..4SZ)
    double* Rc  = (double*)(ws + 4 * SZ);                           // 8 MB (inside V region)
    char* p = ws + 5 * SZ;
    float* Mst  = (float*)p; p += (size_t)NBH * TSEQ * sizeof(float);   // 256 KB
    float* Wst  = (float*)p; p += (size_t)NBH * TSEQ * sizeof(float);   // 256 KB
    float* invn = (float*)p; p += (size_t)NBH * TSEQ * sizeof(float);   // 256 KB
    int*   bucket = (int*)p; p += (size_t)NBH * NHASH * TSEQ * sizeof(int);
    int*   st     = (int*)p; p += (size_t)NBH * NHASH * TSEQ * sizeof(int);

    const int MROWS = BSZ * TSEQ;    // 8192
    const int NELEM = MROWS * DIMM;  // 8388608
    const int NMW = NBH * TSEQ;      // 65536

    init_kernel<<<(NELEM + 255) / 256, 256, 0, stream>>>(x, X1, X2, NELEM);

    for (int l = 0; l < 2; l++) {
        const float* wqk = Wqk + (size_t)l * DIMM * DIMM;
        const float* wv  = Wv  + (size_t)l * DIMM * DIMM;
        const float* wo  = Wo  + (size_t)l * DIMM * DIMM;
        const float* w1  = W1  + (size_t)l * DIMM * FFD;
        const float* w2  = W2  + (size_t)l * FFD * DIMM;
        const float* rotl = rot + (size_t)l * DH * NHASH * (NBUCK / 2);

        // ---- bucketing first (uses 2SZ..4SZ+8MB scratch while it's dead) ----
        ln64_kernel<<<MROWS, 256, 0, stream>>>(X2, ln1g + l * DIMM, ln1b + l * DIMM, H64);
        rcomb_kernel<<<DIMM, 256, 0, stream>>>(wqk, rotl, Rc);
        rotgemm_kernel<<<dim3(8, 64), 256, 0, stream>>>(H64, Rc, bucket);

        // ---- attention: a = LSHAttn(LN(x2)); y1 = x1 + a ----
        ln_bf16_kernel<<<MROWS, 256, 0, stream>>>(X2, ln1g + l * DIMM, ln1b + l * DIMM, Hb);
        convT_kernel<<<dim3(32, 32), 256, 0, stream>>>(wqk, Wb, DIMM, DIMM);
        mgemm_kernel<0><<<dim3(8, 64), 256, 0, stream>>>(Hb, Wb, nullptr, nullptr, QK,
                                                         MROWS, DIMM, DIMM, 0);
        convT_kernel<<<dim3(32, 32), 256, 0, stream>>>(wv, Wb, DIMM, DIMM);
        mgemm_kernel<0><<<dim3(8, 64), 256, 0, stream>>>(Hb, Wb, nullptr, nullptr, V,
                                                         MROWS, DIMM, DIMM, 0);
        sort_kernel<<<dim3(NHASH, NBH), 64, 0, stream>>>(bucket, st);
        norm_kernel<<<dim3(TSEQ / 4, NBH), 256, 0, stream>>>(QK, invn);
        initmw_kernel<<<(NMW + 255) / 256, 256, 0, stream>>>(Mst, Wst, NMW);
        zero_kernel<<<(NELEM + 255) / 256, 256, 0, stream>>>(AO, NELEM);
        for (int r = 0; r < NHASH; r++)
            attn_online_kernel<<<dim3(NBUCK, NBH), 256, 0, stream>>>(
                QK, V, invn, st, Mst, Wst, AO, r * NBUCK);
        div_kernel<<<(NELEM + 255) / 256, 256, 0, stream>>>(AO, Wst, AOb, NELEM);
        convT_kernel<<<dim3(32, 32), 256, 0, stream>>>(wo, Wob, DIMM, DIMM);
        mgemm_kernel<0><<<dim3(8, 64), 256, 0, stream>>>(AOb, Wob, bo + l * DIMM, X1, X1,
                                                         MROWS, DIMM, DIMM, 1 | 4);

        // ---- feed-forward: y2 = x2 + FF(LN(y1)) ----
        ln_bf16_kernel<<<MROWS, 256, 0, stream>>>(X1, ln2g + l * DIMM, ln2b + l * DIMM, Hb2);
        convT_kernel<<<dim3(128, 32), 256, 0, stream>>>(w1, W1b, DIMM, FFD);
        mgemm_kernel<1><<<dim3(32, 64), 256, 0, stream>>>(Hb2, W1b, b1 + l * FFD, nullptr, G,
                                                          MROWS, FFD, DIMM, 1 | 2);
        convT_kernel<<<dim3(32, 128), 256, 0, stream>>>(w2, W2b, FFD, DIMM);
        mgemm_kernel<0><<<dim3(8, 64), 256, 0, stream>>>(G, W2b, b2 + l * DIMM, X2, X2,
                                                         MROWS, DIMM, FFD, 1 | 4);
    }

    final_kernel<<<(NELEM + 255) / 256, 256, 0, stream>>>(X1, X2, out, NELEM);
}

// Round 6
// 3036.156 us; speedup vs baseline: 1.4222x; 1.1327x over previous
//
#include <hip/hip_runtime.h>
#include <hip/hip_bf16.h>

// ---------------- model constants ----------------
#define TSEQ   4096
#define DIMM   1024
#define NHEADS 8
#define DH     128
#define NHASH  4
#define NBUCK  64
#define NCHUNK 256           // NHASH * NBUCK chunks of 64 sorted positions
#define BSZ    2
#define NBH    16            // BSZ * NHEADS
#define FFD    4096

typedef __attribute__((ext_vector_type(4))) float f32x4;
typedef __attribute__((ext_vector_type(8))) short s16x8;
typedef __attribute__((ext_vector_type(4))) short s16x4;
typedef __attribute__((ext_vector_type(2))) double f64x2;

__device__ __forceinline__ unsigned short f2bf(float f) {
    union { float f; unsigned int u; } x; x.f = f;
    unsigned int r = x.u + 0x7FFFu + ((x.u >> 16) & 1u);   // RNE
    return (unsigned short)(r >> 16);
}

__device__ __forceinline__ void async16(const void* g, void* l) {
    __builtin_amdgcn_global_load_lds(
        (const __attribute__((address_space(1))) unsigned int*)g,
        (__attribute__((address_space(3))) unsigned int*)l, 16, 0, 0);
}

__device__ __forceinline__ float gelu_tanh(float x) {
    float x3 = x * x * x;
    float inner = 0.7978845608028654f * (x + 0.044715f * x3);
    return 0.5f * x * (1.0f + tanhf(inner));
}

// ---------------- init / zero / converts ----------------
__global__ void init_kernel(const float* __restrict__ x, float* __restrict__ X1,
                            float* __restrict__ X2, int n) {
    int i = blockIdx.x * blockDim.x + threadIdx.x;
    if (i < n) { float v = x[i]; X1[i] = v; X2[i] = v; }
}

__global__ void zero_kernel(float* __restrict__ p, int n) {
    int i = blockIdx.x * blockDim.x + threadIdx.x;
    if (i < n) p[i] = 0.f;
}

__global__ void initmw_kernel(float* __restrict__ M, float* __restrict__ W, int n) {
    int i = blockIdx.x * blockDim.x + threadIdx.x;
    if (i < n) { M[i] = -3.0e38f; W[i] = 0.f; }
}

// AOb = bf16(U / Wsum)
__global__ void div_kernel(const float* __restrict__ U, const float* __restrict__ Wst,
                           unsigned short* __restrict__ AOb, int n) {
    int i = blockIdx.x * blockDim.x + threadIdx.x;
    if (i < n) {
        int row = i >> 10, col = i & 1023;
        int b = row >> 12, t = row & 4095, head = col >> 7;
        float w = Wst[(size_t)(b * 8 + head) * TSEQ + t];
        AOb[i] = f2bf(U[i] / w);
    }
}

// convert + transpose: in[K x N] fp32 -> out[N x K] bf16
__global__ __launch_bounds__(256) void convT_kernel(const float* __restrict__ in,
                                                    unsigned short* __restrict__ out,
                                                    int K, int N) {
    __shared__ float tile[32][33];
    int n0 = blockIdx.x * 32, k0 = blockIdx.y * 32;
    int tx = threadIdx.x & 31, ty = threadIdx.x >> 5;
    #pragma unroll
    for (int r = 0; r < 4; r++)
        tile[ty + r * 8][tx] = in[(size_t)(k0 + ty + r * 8) * N + n0 + tx];
    __syncthreads();
    #pragma unroll
    for (int r = 0; r < 4; r++)
        out[(size_t)(n0 + ty + r * 8) * K + k0 + tx] = f2bf(tile[tx][ty + r * 8]);
}

// ---------------- layernorm -> bf16 out ----------------
__global__ __launch_bounds__(256) void ln_bf16_kernel(const float* __restrict__ in,
                                                      const float* __restrict__ g,
                                                      const float* __restrict__ bb,
                                                      unsigned short* __restrict__ out) {
    int row = blockIdx.x;
    int tid = threadIdx.x;
    const float* xr = in + (size_t)row * DIMM;
    float v[4];
    float s = 0.f, sq = 0.f;
    #pragma unroll
    for (int k = 0; k < 4; k++) { float t = xr[tid + 256 * k]; v[k] = t; s += t; sq += t * t; }
    __shared__ float rs[256], rq[256];
    rs[tid] = s; rq[tid] = sq; __syncthreads();
    for (int off = 128; off > 0; off >>= 1) {
        if (tid < off) { rs[tid] += rs[tid + off]; rq[tid] += rq[tid + off]; }
        __syncthreads();
    }
    float mu  = rs[0] * (1.f / DIMM);
    float var = rq[0] * (1.f / DIMM) - mu * mu;
    float rstd = rsqrtf(var + 1e-5f);
    unsigned short* orow = out + (size_t)row * DIMM;
    #pragma unroll
    for (int k = 0; k < 4; k++) {
        int c = tid + 256 * k;
        orow[c] = f2bf((v[k] - mu) * rstd * g[c] + bb[c]);
    }
}

// ---------------- bf16 MFMA GEMM: C = A @ B [+bias][gelu][+resid] ----------------
template<int OUT_BF16>
__global__ __launch_bounds__(256) void mgemm_kernel(const unsigned short* __restrict__ A,
                                                    const unsigned short* __restrict__ Bt,
                                                    const float* __restrict__ bias,
                                                    const float* __restrict__ resid,
                                                    void* __restrict__ Cv,
                                                    int M, int N, int K, int flags) {
    __shared__ __align__(16) unsigned short sA[128 * 32];
    __shared__ __align__(16) unsigned short sB[128 * 32];
    int tid = threadIdx.x;
    int wave = tid >> 6, lane = tid & 63;
    int n0 = blockIdx.x * 128, m0 = blockIdx.y * 128;
    int wr = (wave >> 1) * 64, wc = (wave & 1) * 64;
    f32x4 acc[4][4] = {};
    int c1 = tid, c2 = tid + 256;
    const unsigned short* gA1 = A + (size_t)(m0 + (c1 >> 2)) * K + (c1 & 3) * 8;
    const unsigned short* gA2 = A + (size_t)(m0 + (c2 >> 2)) * K + (c2 & 3) * 8;
    const unsigned short* gB1 = Bt + (size_t)(n0 + (c1 >> 2)) * K + (c1 & 3) * 8;
    const unsigned short* gB2 = Bt + (size_t)(n0 + (c2 >> 2)) * K + (c2 & 3) * 8;
    unsigned short* lA1 = sA + wave * 512;
    unsigned short* lA2 = sA + 2048 + wave * 512;
    unsigned short* lB1 = sB + wave * 512;
    unsigned short* lB2 = sB + 2048 + wave * 512;
    int qk8 = (lane >> 4) * 8;
    int r16 = lane & 15;
    for (int k0 = 0; k0 < K; k0 += 32) {
        __syncthreads();
        async16(gA1 + k0, lA1);
        async16(gA2 + k0, lA2);
        async16(gB1 + k0, lB1);
        async16(gB2 + k0, lB2);
        __syncthreads();
        s16x8 af[4], bf[4];
        #pragma unroll
        for (int i = 0; i < 4; i++) {
            af[i] = *(const s16x8*)&sA[(wr + i * 16 + r16) * 32 + qk8];
            bf[i] = *(const s16x8*)&sB[(wc + i * 16 + r16) * 32 + qk8];
        }
        #pragma unroll
        for (int mi = 0; mi < 4; mi++)
            #pragma unroll
            for (int ni = 0; ni < 4; ni++)
                acc[mi][ni] = __builtin_amdgcn_mfma_f32_16x16x32_bf16(af[mi], bf[ni], acc[mi][ni], 0, 0, 0);
    }
    #pragma unroll
    for (int mi = 0; mi < 4; mi++) {
        #pragma unroll
        for (int r = 0; r < 4; r++) {
            int row = m0 + wr + mi * 16 + (lane >> 4) * 4 + r;
            #pragma unroll
            for (int ni = 0; ni < 4; ni++) {
                int col = n0 + wc + ni * 16 + (lane & 15);
                float v = acc[mi][ni][r];
                if (flags & 1) v += bias[col];
                if (flags & 2) v = gelu_tanh(v);
                if (flags & 4) v += resid[(size_t)row * N + col];
                if (OUT_BF16) ((unsigned short*)Cv)[(size_t)row * N + col] = f2bf(v);
                else          ((float*)Cv)[(size_t)row * N + col] = v;
            }
        }
    }
}

// ---------------- bucketing path: LN64 + combined-projection fp64 GEMM -----------
// (verified structure, unchanged from round 4)

// LN in fp64 -> H64
__global__ __launch_bounds__(256) void ln64_kernel(const float* __restrict__ X,
                                                   const float* __restrict__ g,
                                                   const float* __restrict__ bb,
                                                   double* __restrict__ H64) {
    int row = blockIdx.x;
    int tid = threadIdx.x;
    const float* xr = X + (size_t)row * DIMM;
    __shared__ double rs[256], rq[256];
    double v[4];
    double s = 0.0, sq = 0.0;
    #pragma unroll
    for (int q = 0; q < 4; q++) {
        double t = (double)xr[tid + 256 * q];
        v[q] = t; s += t; sq += t * t;
    }
    rs[tid] = s; rq[tid] = sq; __syncthreads();
    for (int off = 128; off > 0; off >>= 1) {
        if (tid < off) { rs[tid] += rs[tid + off]; rq[tid] += rq[tid + off]; }
        __syncthreads();
    }
    double mu   = rs[0] * (1.0 / DIMM);
    double var  = rq[0] * (1.0 / DIMM) - mu * mu;
    double rstd = 1.0 / sqrt(var + 1e-5);
    double* orow = H64 + (size_t)row * DIMM;
    #pragma unroll
    for (int q = 0; q < 4; q++) {
        int c = tid + 256 * q;
        orow[c] = (v[q] - mu) * rstd * (double)g[c] + (double)bb[c];
    }
}

// R[k][hd*128 + cc] = sum_d Wqk[k][hd*128 + d] * rot[d][cc]   (fp64, serial d)
__global__ __launch_bounds__(256) void rcomb_kernel(const float* __restrict__ Wqk,
                                                    const float* __restrict__ rot,
                                                    double* __restrict__ R) {
    int k = blockIdx.x;                 // 0..1023
    int c0 = threadIdx.x * 4;           // 0..1020
    int hd = c0 >> 7;
    int cc = c0 & 127;
    const float* wrow = Wqk + (size_t)k * DIMM + hd * 128;
    double a0 = 0.0, a1 = 0.0, a2 = 0.0, a3 = 0.0;
    for (int d = 0; d < 128; d++) {
        double w = (double)wrow[d];
        f32x4 r4 = *(const f32x4*)&rot[d * 128 + cc];
        a0 += w * (double)r4.x; a1 += w * (double)r4.y;
        a2 += w * (double)r4.z; a3 += w * (double)r4.w;
    }
    double* orow = R + (size_t)k * DIMM + c0;
    orow[0] = a0; orow[1] = a1; orow[2] = a2; orow[3] = a3;
}

// Tiled fp64 GEMM (8192x1024x1024) with fused per-(head,hash) argmax -> bucket.
#define RKS 8
__global__ __launch_bounds__(256, 2) void rotgemm_kernel(const double* __restrict__ H64,
                                                         const double* __restrict__ R,
                                                         int* __restrict__ bucket) {
    __shared__ double sA[RKS][130];   // [k][m], pitch 130 (1040B rows)
    __shared__ double sB[RKS][130];   // [k][n]
    int tid = threadIdx.x;
    int tx = tid & 15, ty = tid >> 4;
    int n0 = blockIdx.x * 128, m0 = blockIdx.y * 128;
    double acc[8][8] = {};            // [r][c]: row = ty*8+r, col = tx + 16*c

    int arow = tid >> 1, ak = (tid & 1) * 4;           // A stage: 4 fp64 / thread
    const double* gA = H64 + (size_t)(m0 + arow) * DIMM + ak;
    int bkk = tid >> 5, bn = (tid & 31) * 4;           // B stage: 4 fp64 / thread
    const double* gB = R + (size_t)bkk * DIMM + n0 + bn;

    // prefetch tile 0 into registers
    f64x2 a2[2], b2[2];
    a2[0] = *(const f64x2*)(gA);
    a2[1] = *(const f64x2*)(gA + 2);
    b2[0] = *(const f64x2*)(gB);
    b2[1] = *(const f64x2*)(gB + 2);

    for (int k0 = 0; k0 < DIMM; k0 += RKS) {
        __syncthreads();
        sA[ak + 0][arow] = a2[0].x;
        sA[ak + 1][arow] = a2[0].y;
        sA[ak + 2][arow] = a2[1].x;
        sA[ak + 3][arow] = a2[1].y;
        *(f64x2*)&sB[bkk][bn]     = b2[0];
        *(f64x2*)&sB[bkk][bn + 2] = b2[1];
        __syncthreads();
        // prefetch next tile (overlaps the compute phase below)
        if (k0 + RKS < DIMM) {
            const double* pa = gA + k0 + RKS;
            a2[0] = *(const f64x2*)(pa);
            a2[1] = *(const f64x2*)(pa + 2);
            const double* pb = gB + (size_t)(k0 + RKS) * DIMM;
            b2[0] = *(const f64x2*)(pb);
            b2[1] = *(const f64x2*)(pb + 2);
        }
        #pragma unroll
        for (int kk = 0; kk < RKS; kk++) {
            double a_[8], b_[8];
            #pragma unroll
            for (int u = 0; u < 4; u++) {
                f64x2 t = *(const f64x2*)&sA[kk][ty * 8 + 2 * u];
                a_[2 * u] = t.x; a_[2 * u + 1] = t.y;
            }
            #pragma unroll
            for (int c = 0; c < 8; c++) b_[c] = sB[kk][tx + 16 * c];
            #pragma unroll
            for (int r = 0; r < 8; r++)
                #pragma unroll
                for (int c = 0; c < 8; c++)
                    acc[r][c] += a_[r] * b_[c];
        }
    }

    // ---- fused argmax over 64 candidates (+cols 0..31, -cols -> idx 32..63) ----
    int hd = n0 >> 7;
    #pragma unroll
    for (int g = 0; g < 4; g++) {
        #pragma unroll
        for (int r = 0; r < 8; r++) {
            double best = acc[r][2 * g]; int bidx = tx;
            double v1 = acc[r][2 * g + 1];
            if (v1 > best) { best = v1; bidx = tx + 16; }
            double v2 = -acc[r][2 * g];
            if (v2 > best) { best = v2; bidx = 32 + tx; }
            double v3 = -acc[r][2 * g + 1];
            if (v3 > best) { best = v3; bidx = 48 + tx; }
            #pragma unroll
            for (int off = 1; off < 16; off <<= 1) {
                double ov = __shfl_xor(best, off, 64);
                int    oi = __shfl_xor(bidx, off, 64);
                if (ov > best || (ov == best && oi < bidx)) { best = ov; bidx = oi; }
            }
            if (tx == 0) {
                int row = m0 + ty * 8 + r;
                int b_ = row >> 12, t = row & 4095;
                bucket[(size_t)((b_ * 8 + hd) * NHASH + g) * TSEQ + t] = bidx;
            }
        }
    }
}

// ---------------- stable counting sort per (bh, hash round) ----------------
__global__ __launch_bounds__(64) void sort_kernel(const int* __restrict__ bucket,
                                                  int* __restrict__ st) {
    int h = blockIdx.x, bh = blockIdx.y;
    int tid = threadIdx.x;
    __shared__ int sbuck[TSEQ];
    __shared__ int cnt[NBUCK];
    cnt[tid] = 0;
    __syncthreads();
    const int* brow = bucket + (size_t)(bh * NHASH + h) * TSEQ;
    for (int t = tid; t < TSEQ; t += 64) {
        int bu = brow[t];
        sbuck[t] = bu;
        atomicAdd(&cnt[bu], 1);
    }
    __syncthreads();
    if (tid == 0) {
        int run = 0;
        for (int i = 0; i < NBUCK; i++) { int c = cnt[i]; cnt[i] = run; run += c; }
    }
    __syncthreads();
    int off = cnt[tid];
    int* strow = st + (size_t)bh * (NHASH * TSEQ) + h * TSEQ;
    for (int t = 0; t < TSEQ; t++) {
        if (sbuck[t] == tid) strow[off++] = t;
    }
}

// ---------------- per-token key inverse norms ----------------
__global__ __launch_bounds__(256) void norm_kernel(const float* __restrict__ QK,
                                                   float* __restrict__ invn) {
    int bh = blockIdx.y;
    int b = bh >> 3, head = bh & 7;
    int wave = threadIdx.x >> 6, lane = threadIdx.x & 63;
    int t = blockIdx.x * 4 + wave;
    const float* row = QK + (size_t)(b * TSEQ + t) * DIMM + head * DH;
    float v0 = row[lane], v1 = row[lane + 64];
    float s = v0 * v0 + v1 * v1;
    #pragma unroll
    for (int off = 32; off > 0; off >>= 1) s += __shfl_xor(s, off, 64);
    if (lane == 0) invn[bh * TSEQ + t] = rsqrtf(s + 1e-12f);
}

// ---------------- chunked LSH attention v2: MFMA QK^T and PV -------------------
// Same math as the verified scalar version except QK, P, V are quantized to bf16
// as MFMA inputs (fp32 accumulate). sinv/scale/mask applied to fp32 accumulators;
// softmax + online merge code verbatim. Fragment addressing mirrors mgemm_kernel
// (A: lane&15 -> row, (lane>>4)*8 -> k; C: row=(lane>>4)*4+r, col=lane&15).
__global__ __launch_bounds__(256) void attn_online_kernel(const float* __restrict__ QK,
                                                          const float* __restrict__ V,
                                                          const float* __restrict__ invn,
                                                          const int* __restrict__ st,
                                                          float* __restrict__ Mst,
                                                          float* __restrict__ Wst,
                                                          float* __restrict__ U,
                                                          int roundBase) {
    int c  = roundBase + blockIdx.x;   // global chunk id
    int bh = blockIdx.y;
    int b = bh >> 3, head = bh & 7;
    const float* QKb = QK + (size_t)b * TSEQ * DIMM + head * DH;
    const float* Vb  = V  + (size_t)b * TSEQ * DIMM + head * DH;
    const int* stb = st + (size_t)bh * (NHASH * TSEQ);
    int prev = (c + NCHUNK - 1) & (NCHUNK - 1);
    int tid = threadIdx.x;
    int wave = tid >> 6, lane = tid & 63;
    int l16 = lane & 15, hi4 = lane >> 4;

    __shared__ __align__(16) unsigned short sKb[128][136];  // raw bf16 rows; 0..63 = Q
    __shared__ __align__(16) float sdots[64][132];
    __shared__ __align__(16) unsigned short sVt[128][36];   // V^T tile: [d][j in 32-tile]
    __shared__ int   sbt[64];
    __shared__ int   sbkt[128];
    __shared__ float sinv[128];
    __shared__ float sa[64], sb[64];

    if (tid < 64) sbt[tid] = stb[c * 64 + tid];
    if (tid < 128) {
        int j = tid;
        int p = (j < 64) ? (c * 64 + j) : (prev * 64 + j - 64);
        int tk = stb[p];
        sbkt[j] = tk;
        sinv[j] = invn[bh * TSEQ + tk];
    }
    __syncthreads();

    // ---- stage all 128 K rows (rows 0..63 are the Q rows) fp32->bf16 ----
    #pragma unroll
    for (int pass = 0; pass < 16; pass++) {
        int idx = pass * 256 + tid;          // 0..4095 chunks of f32x4
        int j = idx >> 5, dq = (idx & 31) * 4;
        f32x4 v4 = *(const f32x4*)&QKb[(size_t)sbkt[j] * DIMM + dq];
        unsigned short* p = &sKb[j][dq];
        p[0] = f2bf(v4.x); p[1] = f2bf(v4.y); p[2] = f2bf(v4.z); p[3] = f2bf(v4.w);
    }
    __syncthreads();

    // ---- QK^T: wave w computes rows [16w,16w+16) x all 128 cols ----
    f32x4 dacc[8] = {};
    #pragma unroll
    for (int k0 = 0; k0 < 128; k0 += 32) {
        s16x8 afr = *(const s16x8*)&sKb[16 * wave + l16][k0 + hi4 * 8];
        #pragma unroll
        for (int t = 0; t < 8; t++) {
            s16x8 bfr = *(const s16x8*)&sKb[16 * t + l16][k0 + hi4 * 8];
            dacc[t] = __builtin_amdgcn_mfma_f32_16x16x32_bf16(afr, bfr, dacc[t], 0, 0, 0);
        }
    }
    const float scale = 0.08838834764831845f;
    #pragma unroll
    for (int t = 0; t < 8; t++) {
        #pragma unroll
        for (int r = 0; r < 4; r++) {
            int i = 16 * wave + hi4 * 4 + r;
            int j = 16 * t + l16;
            float v = dacc[t][r] * sinv[j] * scale;
            if (sbt[i] == sbkt[j]) v -= 1e5f;
            sdots[i][j] = v;
        }
    }
    __syncthreads();

    // ---- row softmax + online merge factors (verbatim) ----
    if (tid < 64) {
        float m = -3.402823466e38f;
        for (int j = 0; j < 128; j++) m = fmaxf(m, sdots[tid][j]);
        float s = 0.f;
        for (int j = 0; j < 128; j++) s += expf(sdots[tid][j] - m);
        float inv = 1.f / s;
        for (int j = 0; j < 128; j++) sdots[tid][j] = expf(sdots[tid][j] - m) * inv;
        float lse = m + logf(s);
        int tok = sbt[tid];
        size_t mi = (size_t)bh * TSEQ + tok;
        float oldM = Mst[mi], oldW = Wst[mi];
        float newM = fmaxf(oldM, lse);
        float af = expf(oldM - newM);
        float bf = expf(lse - newM);
        Mst[mi] = newM;
        Wst[mi] = oldW * af + bf;
        sa[tid] = af; sb[tid] = bf;
    }
    __syncthreads();

    // ---- PV: O[i][d] = sum_j P[i][j] V[j][d], per 32-wide j-tile ----
    f32x4 oacc[8] = {};
    for (int j0 = 0; j0 < 128; j0 += 32) {
        __syncthreads();   // protect sVt from previous tile's readers
        // stage V^T tile: 32 j-rows x 128 d (coalesced global, bf16 transpose write)
        #pragma unroll
        for (int pass = 0; pass < 16; pass++) {
            int idx = pass * 256 + tid;      // 0..4095
            int jj = idx >> 7, d = idx & 127;
            sVt[d][jj] = f2bf(Vb[(size_t)sbkt[j0 + jj] * DIMM + d]);
        }
        __syncthreads();
        // A-frag: P row slice -> bf16 in-register
        float pv[8];
        *(f32x4*)&pv[0] = *(const f32x4*)&sdots[16 * wave + l16][j0 + hi4 * 8];
        *(f32x4*)&pv[4] = *(const f32x4*)&sdots[16 * wave + l16][j0 + hi4 * 8 + 4];
        s16x8 pfr;
        #pragma unroll
        for (int u = 0; u < 8; u++) pfr[u] = (short)f2bf(pv[u]);
        #pragma unroll
        for (int t = 0; t < 8; t++) {
            s16x4 vlo = *(const s16x4*)&sVt[16 * t + l16][hi4 * 8];
            s16x4 vhi = *(const s16x4*)&sVt[16 * t + l16][hi4 * 8 + 4];
            s16x8 vfr;
            vfr[0] = vlo[0]; vfr[1] = vlo[1]; vfr[2] = vlo[2]; vfr[3] = vlo[3];
            vfr[4] = vhi[0]; vfr[5] = vhi[1]; vfr[6] = vhi[2]; vfr[7] = vhi[3];
            oacc[t] = __builtin_amdgcn_mfma_f32_16x16x32_bf16(pfr, vfr, oacc[t], 0, 0, 0);
        }
    }

    // ---- U update: U = U*a + O*b ----
    #pragma unroll
    for (int t = 0; t < 8; t++) {
        #pragma unroll
        for (int r = 0; r < 4; r++) {
            int i = 16 * wave + hi4 * 4 + r;
            float af = sa[i], bf = sb[i];
            int d = 16 * t + l16;
            float* urow = U + (size_t)(b * TSEQ + sbt[i]) * DIMM + head * DH;
            urow[d] = urow[d] * af + oacc[t][r] * bf;
        }
    }
}

// ---------------- final: out = 0.5*(X1+X2), fp32 ----------------
__global__ void final_kernel(const float* __restrict__ X1, const float* __restrict__ X2,
                             float* __restrict__ out, int n) {
    int i = blockIdx.x * blockDim.x + threadIdx.x;
    if (i < n) out[i] = 0.5f * (X1[i] + X2[i]);
}

extern "C" void kernel_launch(void* const* d_in, const int* in_sizes, int n_in,
                              void* d_out, int out_size, void* d_ws, size_t ws_size,
                              hipStream_t stream) {
    (void)in_sizes; (void)n_in; (void)out_size; (void)ws_size;
    const float* x    = (const float*)d_in[0];
    const float* ln1g = (const float*)d_in[2];
    const float* ln1b = (const float*)d_in[3];
    const float* Wqk  = (const float*)d_in[4];
    const float* Wv   = (const float*)d_in[5];
    const float* Wo   = (const float*)d_in[6];
    const float* bo   = (const float*)d_in[7];
    const float* ln2g = (const float*)d_in[8];
    const float* ln2b = (const float*)d_in[9];
    const float* W1   = (const float*)d_in[10];
    const float* b1   = (const float*)d_in[11];
    const float* W2   = (const float*)d_in[12];
    const float* b2   = (const float*)d_in[13];
    const float* rot  = (const float*)d_in[14];
    float* out = (float*)d_out;

    // ---- workspace layout (163.1 MB, same known-good footprint) ----
    char* ws = (char*)d_ws;
    const size_t SZ  = (size_t)BSZ * TSEQ * DIMM * sizeof(float);   // 32 MB
    const size_t HSZ = SZ / 2;                                      // 16 MB
    float* X1 = (float*)(ws + 0 * SZ);
    float* X2 = (float*)(ws + 1 * SZ);
    unsigned short* Hb  = (unsigned short*)(ws + 2 * SZ);           // LN out bf16
    unsigned short* Wb  = (unsigned short*)(ws + 2 * SZ + HSZ);     // weight bf16
    float* AO = (float*)(ws + 2 * SZ);                              // U accumulator fp32
    float* QK = (float*)(ws + 3 * SZ);
    unsigned short* AOb = (unsigned short*)(ws + 3 * SZ);
    unsigned short* Wob = (unsigned short*)(ws + 3 * SZ + HSZ);
    float* V = (float*)(ws + 4 * SZ);
    unsigned short* Hb2 = (unsigned short*)(ws + 4 * SZ);
    unsigned short* W1b = (unsigned short*)(ws + 4 * SZ + HSZ);
    unsigned short* W2b = (unsigned short*)(ws + 4 * SZ + HSZ + 8 * 1024 * 1024);
    unsigned short* G = (unsigned short*)(ws + 2 * SZ);             // FF hidden bf16 64MB
    // bucket-path scratch (live only at start of each layer, before Hb/QK/V):
    double* H64 = (double*)(ws + 2 * SZ);                           // 64 MB (2SZ..4SZ)
    double* Rc  = (double*)(ws + 4 * SZ);                           // 8 MB (inside V region)
    char* p = ws + 5 * SZ;
    float* Mst  = (float*)p; p += (size_t)NBH * TSEQ * sizeof(float);   // 256 KB
    float* Wst  = (float*)p; p += (size_t)NBH * TSEQ * sizeof(float);   // 256 KB
    float* invn = (float*)p; p += (size_t)NBH * TSEQ * sizeof(float);   // 256 KB
    int*   bucket = (int*)p; p += (size_t)NBH * NHASH * TSEQ * sizeof(int);
    int*   st     = (int*)p; p += (size_t)NBH * NHASH * TSEQ * sizeof(int);

    const int MROWS = BSZ * TSEQ;    // 8192
    const int NELEM = MROWS * DIMM;  // 8388608
    const int NMW = NBH * TSEQ;      // 65536

    init_kernel<<<(NELEM + 255) / 256, 256, 0, stream>>>(x, X1, X2, NELEM);

    for (int l = 0; l < 2; l++) {
        const float* wqk = Wqk + (size_t)l * DIMM * DIMM;
        const float* wv  = Wv  + (size_t)l * DIMM * DIMM;
        const float* wo  = Wo  + (size_t)l * DIMM * DIMM;
        const float* w1  = W1  + (size_t)l * DIMM * FFD;
        const float* w2  = W2  + (size_t)l * FFD * DIMM;
        const float* rotl = rot + (size_t)l * DH * NHASH * (NBUCK / 2);

        // ---- bucketing first (uses 2SZ..4SZ+8MB scratch while it's dead) ----
        ln64_kernel<<<MROWS, 256, 0, stream>>>(X2, ln1g + l * DIMM, ln1b + l * DIMM, H64);
        rcomb_kernel<<<DIMM, 256, 0, stream>>>(wqk, rotl, Rc);
        rotgemm_kernel<<<dim3(8, 64), 256, 0, stream>>>(H64, Rc, bucket);

        // ---- attention: a = LSHAttn(LN(x2)); y1 = x1 + a ----
        ln_bf16_kernel<<<MROWS, 256, 0, stream>>>(X2, ln1g + l * DIMM, ln1b + l * DIMM, Hb);
        convT_kernel<<<dim3(32, 32), 256, 0, stream>>>(wqk, Wb, DIMM, DIMM);
        mgemm_kernel<0><<<dim3(8, 64), 256, 0, stream>>>(Hb, Wb, nullptr, nullptr, QK,
                                                         MROWS, DIMM, DIMM, 0);
        convT_kernel<<<dim3(32, 32), 256, 0, stream>>>(wv, Wb, DIMM, DIMM);
        mgemm_kernel<0><<<dim3(8, 64), 256, 0, stream>>>(Hb, Wb, nullptr, nullptr, V,
                                                         MROWS, DIMM, DIMM, 0);
        sort_kernel<<<dim3(NHASH, NBH), 64, 0, stream>>>(bucket, st);
        norm_kernel<<<dim3(TSEQ / 4, NBH), 256, 0, stream>>>(QK, invn);
        initmw_kernel<<<(NMW + 255) / 256, 256, 0, stream>>>(Mst, Wst, NMW);
        zero_kernel<<<(NELEM + 255) / 256, 256, 0, stream>>>(AO, NELEM);
        for (int r = 0; r < NHASH; r++)
            attn_online_kernel<<<dim3(NBUCK, NBH), 256, 0, stream>>>(
                QK, V, invn, st, Mst, Wst, AO, r * NBUCK);
        div_kernel<<<(NELEM + 255) / 256, 256, 0, stream>>>(AO, Wst, AOb, NELEM);
        convT_kernel<<<dim3(32, 32), 256, 0, stream>>>(wo, Wob, DIMM, DIMM);
        mgemm_kernel<0><<<dim3(8, 64), 256, 0, stream>>>(AOb, Wob, bo + l * DIMM, X1, X1,
                                                         MROWS, DIMM, DIMM, 1 | 4);

        // ---- feed-forward: y2 = x2 + FF(LN(y1)) ----
        ln_bf16_kernel<<<MROWS, 256, 0, stream>>>(X1, ln2g + l * DIMM, ln2b + l * DIMM, Hb2);
        convT_kernel<<<dim3(128, 32), 256, 0, stream>>>(w1, W1b, DIMM, FFD);
        mgemm_kernel<1><<<dim3(32, 64), 256, 0, stream>>>(Hb2, W1b, b1 + l * FFD, nullptr, G,
                                                          MROWS, FFD, DIMM, 1 | 2);
        convT_kernel<<<dim3(32, 128), 256, 0, stream>>>(w2, W2b, FFD, DIMM);
        mgemm_kernel<0><<<dim3(8, 64), 256, 0, stream>>>(G, W2b, b2 + l * DIMM, X2, X2,
                                                         MROWS, DIMM, FFD, 1 | 4);
    }

    final_kernel<<<(NELEM + 255) / 256, 256, 0, stream>>>(X1, X2, out, NELEM);
}

// Round 7
// 2992.475 us; speedup vs baseline: 1.4429x; 1.0146x over previous
//
#include <hip/hip_runtime.h>
#include <hip/hip_bf16.h>

// ---------------- model constants ----------------
#define TSEQ   4096
#define DIMM   1024
#define NHEADS 8
#define DH     128
#define NHASH  4
#define NBUCK  64
#define NCHUNK 256           // NHASH * NBUCK chunks of 64 sorted positions
#define BSZ    2
#define NBH    16            // BSZ * NHEADS
#define FFD    4096

typedef __attribute__((ext_vector_type(4))) float f32x4;
typedef __attribute__((ext_vector_type(8))) short s16x8;
typedef __attribute__((ext_vector_type(4))) short s16x4;
typedef __attribute__((ext_vector_type(2))) double f64x2;

__device__ __forceinline__ unsigned short f2bf(float f) {
    union { float f; unsigned int u; } x; x.f = f;
    unsigned int r = x.u + 0x7FFFu + ((x.u >> 16) & 1u);   // RNE
    return (unsigned short)(r >> 16);
}

__device__ __forceinline__ void async16(const void* g, void* l) {
    __builtin_amdgcn_global_load_lds(
        (const __attribute__((address_space(1))) unsigned int*)g,
        (__attribute__((address_space(3))) unsigned int*)l, 16, 0, 0);
}

__device__ __forceinline__ float gelu_tanh(float x) {
    float x3 = x * x * x;
    float inner = 0.7978845608028654f * (x + 0.044715f * x3);
    return 0.5f * x * (1.0f + tanhf(inner));
}

// ---------------- init / zero / converts ----------------
__global__ void init_kernel(const float* __restrict__ x, float* __restrict__ X1,
                            float* __restrict__ X2, int n) {
    int i = blockIdx.x * blockDim.x + threadIdx.x;
    if (i < n) { float v = x[i]; X1[i] = v; X2[i] = v; }
}

__global__ void zero_kernel(float* __restrict__ p, int n) {
    int i = blockIdx.x * blockDim.x + threadIdx.x;
    if (i < n) p[i] = 0.f;
}

__global__ void initmw_kernel(float* __restrict__ M, float* __restrict__ W, int n) {
    int i = blockIdx.x * blockDim.x + threadIdx.x;
    if (i < n) { M[i] = -3.0e38f; W[i] = 0.f; }
}

// AOb = bf16(U / Wsum)
__global__ void div_kernel(const float* __restrict__ U, const float* __restrict__ Wst,
                           unsigned short* __restrict__ AOb, int n) {
    int i = blockIdx.x * blockDim.x + threadIdx.x;
    if (i < n) {
        int row = i >> 10, col = i & 1023;
        int b = row >> 12, t = row & 4095, head = col >> 7;
        float w = Wst[(size_t)(b * 8 + head) * TSEQ + t];
        AOb[i] = f2bf(U[i] / w);
    }
}

// convert + transpose: in[K x N] fp32 -> out[N x K] bf16
__global__ __launch_bounds__(256) void convT_kernel(const float* __restrict__ in,
                                                    unsigned short* __restrict__ out,
                                                    int K, int N) {
    __shared__ float tile[32][33];
    int n0 = blockIdx.x * 32, k0 = blockIdx.y * 32;
    int tx = threadIdx.x & 31, ty = threadIdx.x >> 5;
    #pragma unroll
    for (int r = 0; r < 4; r++)
        tile[ty + r * 8][tx] = in[(size_t)(k0 + ty + r * 8) * N + n0 + tx];
    __syncthreads();
    #pragma unroll
    for (int r = 0; r < 4; r++)
        out[(size_t)(n0 + ty + r * 8) * K + k0 + tx] = f2bf(tile[tx][ty + r * 8]);
}

// ---------------- layernorm -> bf16 out ----------------
__global__ __launch_bounds__(256) void ln_bf16_kernel(const float* __restrict__ in,
                                                      const float* __restrict__ g,
                                                      const float* __restrict__ bb,
                                                      unsigned short* __restrict__ out) {
    int row = blockIdx.x;
    int tid = threadIdx.x;
    const float* xr = in + (size_t)row * DIMM;
    float v[4];
    float s = 0.f, sq = 0.f;
    #pragma unroll
    for (int k = 0; k < 4; k++) { float t = xr[tid + 256 * k]; v[k] = t; s += t; sq += t * t; }
    __shared__ float rs[256], rq[256];
    rs[tid] = s; rq[tid] = sq; __syncthreads();
    for (int off = 128; off > 0; off >>= 1) {
        if (tid < off) { rs[tid] += rs[tid + off]; rq[tid] += rq[tid + off]; }
        __syncthreads();
    }
    float mu  = rs[0] * (1.f / DIMM);
    float var = rq[0] * (1.f / DIMM) - mu * mu;
    float rstd = rsqrtf(var + 1e-5f);
    unsigned short* orow = out + (size_t)row * DIMM;
    #pragma unroll
    for (int k = 0; k < 4; k++) {
        int c = tid + 256 * k;
        orow[c] = f2bf((v[k] - mu) * rstd * g[c] + bb[c]);
    }
}

// ---------------- bf16 MFMA GEMM: C = A @ B [+bias][gelu][+resid] ----------------
template<int OUT_BF16>
__global__ __launch_bounds__(256) void mgemm_kernel(const unsigned short* __restrict__ A,
                                                    const unsigned short* __restrict__ Bt,
                                                    const float* __restrict__ bias,
                                                    const float* __restrict__ resid,
                                                    void* __restrict__ Cv,
                                                    int M, int N, int K, int flags) {
    __shared__ __align__(16) unsigned short sA[128 * 32];
    __shared__ __align__(16) unsigned short sB[128 * 32];
    int tid = threadIdx.x;
    int wave = tid >> 6, lane = tid & 63;
    int n0 = blockIdx.x * 128, m0 = blockIdx.y * 128;
    int wr = (wave >> 1) * 64, wc = (wave & 1) * 64;
    f32x4 acc[4][4] = {};
    int c1 = tid, c2 = tid + 256;
    const unsigned short* gA1 = A + (size_t)(m0 + (c1 >> 2)) * K + (c1 & 3) * 8;
    const unsigned short* gA2 = A + (size_t)(m0 + (c2 >> 2)) * K + (c2 & 3) * 8;
    const unsigned short* gB1 = Bt + (size_t)(n0 + (c1 >> 2)) * K + (c1 & 3) * 8;
    const unsigned short* gB2 = Bt + (size_t)(n0 + (c2 >> 2)) * K + (c2 & 3) * 8;
    unsigned short* lA1 = sA + wave * 512;
    unsigned short* lA2 = sA + 2048 + wave * 512;
    unsigned short* lB1 = sB + wave * 512;
    unsigned short* lB2 = sB + 2048 + wave * 512;
    int qk8 = (lane >> 4) * 8;
    int r16 = lane & 15;
    for (int k0 = 0; k0 < K; k0 += 32) {
        __syncthreads();
        async16(gA1 + k0, lA1);
        async16(gA2 + k0, lA2);
        async16(gB1 + k0, lB1);
        async16(gB2 + k0, lB2);
        __syncthreads();
        s16x8 af[4], bf[4];
        #pragma unroll
        for (int i = 0; i < 4; i++) {
            af[i] = *(const s16x8*)&sA[(wr + i * 16 + r16) * 32 + qk8];
            bf[i] = *(const s16x8*)&sB[(wc + i * 16 + r16) * 32 + qk8];
        }
        #pragma unroll
        for (int mi = 0; mi < 4; mi++)
            #pragma unroll
            for (int ni = 0; ni < 4; ni++)
                acc[mi][ni] = __builtin_amdgcn_mfma_f32_16x16x32_bf16(af[mi], bf[ni], acc[mi][ni], 0, 0, 0);
    }
    #pragma unroll
    for (int mi = 0; mi < 4; mi++) {
        #pragma unroll
        for (int r = 0; r < 4; r++) {
            int row = m0 + wr + mi * 16 + (lane >> 4) * 4 + r;
            #pragma unroll
            for (int ni = 0; ni < 4; ni++) {
                int col = n0 + wc + ni * 16 + (lane & 15);
                float v = acc[mi][ni][r];
                if (flags & 1) v += bias[col];
                if (flags & 2) v = gelu_tanh(v);
                if (flags & 4) v += resid[(size_t)row * N + col];
                if (OUT_BF16) ((unsigned short*)Cv)[(size_t)row * N + col] = f2bf(v);
                else          ((float*)Cv)[(size_t)row * N + col] = v;
            }
        }
    }
}

// ---------------- bucketing path: LN64 + combined-projection fp64 GEMM -----------

// LN in fp64 -> H64
__global__ __launch_bounds__(256) void ln64_kernel(const float* __restrict__ X,
                                                   const float* __restrict__ g,
                                                   const float* __restrict__ bb,
                                                   double* __restrict__ H64) {
    int row = blockIdx.x;
    int tid = threadIdx.x;
    const float* xr = X + (size_t)row * DIMM;
    __shared__ double rs[256], rq[256];
    double v[4];
    double s = 0.0, sq = 0.0;
    #pragma unroll
    for (int q = 0; q < 4; q++) {
        double t = (double)xr[tid + 256 * q];
        v[q] = t; s += t; sq += t * t;
    }
    rs[tid] = s; rq[tid] = sq; __syncthreads();
    for (int off = 128; off > 0; off >>= 1) {
        if (tid < off) { rs[tid] += rs[tid + off]; rq[tid] += rq[tid + off]; }
        __syncthreads();
    }
    double mu   = rs[0] * (1.0 / DIMM);
    double var  = rq[0] * (1.0 / DIMM) - mu * mu;
    double rstd = 1.0 / sqrt(var + 1e-5);
    double* orow = H64 + (size_t)row * DIMM;
    #pragma unroll
    for (int q = 0; q < 4; q++) {
        int c = tid + 256 * q;
        orow[c] = (v[q] - mu) * rstd * (double)g[c] + (double)bb[c];
    }
}

// R[k][hd*128 + cc] = sum_d Wqk[k][hd*128 + d] * rot[d][cc]   (fp64, serial d)
__global__ __launch_bounds__(256) void rcomb_kernel(const float* __restrict__ Wqk,
                                                    const float* __restrict__ rot,
                                                    double* __restrict__ R) {
    int k = blockIdx.x;                 // 0..1023
    int c0 = threadIdx.x * 4;           // 0..1020
    int hd = c0 >> 7;
    int cc = c0 & 127;
    const float* wrow = Wqk + (size_t)k * DIMM + hd * 128;
    double a0 = 0.0, a1 = 0.0, a2 = 0.0, a3 = 0.0;
    for (int d = 0; d < 128; d++) {
        double w = (double)wrow[d];
        f32x4 r4 = *(const f32x4*)&rot[d * 128 + cc];
        a0 += w * (double)r4.x; a1 += w * (double)r4.y;
        a2 += w * (double)r4.z; a3 += w * (double)r4.w;
    }
    double* orow = R + (size_t)k * DIMM + c0;
    orow[0] = a0; orow[1] = a1; orow[2] = a2; orow[3] = a3;
}

// Tiled fp64 GEMM (8192x1024x1024) with fused per-(head,hash) argmax -> bucket.
// v9: same 128x128 block tile / 8x8 per thread / k-ascending per-output chain
// (bit-identical results), but (a) thread's 8 cols are 4 ADJACENT PAIRS
// (2tx+32c+{0,1}) so B fragment reads are 4x ds_read_b128 (banks (4tx)%32,
// 2-way free) instead of 8x ds_read_b64 — v8 was LDS-instruction-rate bound;
// (b) K-step 16 halves barrier count.
#define RKS 16
__global__ __launch_bounds__(256, 2) void rotgemm_kernel(const double* __restrict__ H64,
                                                         const double* __restrict__ R,
                                                         int* __restrict__ bucket) {
    __shared__ double sA[RKS][130];   // [k][m], pitch 130 (1040B rows)
    __shared__ double sB[RKS][130];   // [k][n]
    int tid = threadIdx.x;
    int tx = tid & 15, ty = tid >> 4;
    int n0 = blockIdx.x * 128, m0 = blockIdx.y * 128;
    double acc[8][8] = {};            // [r][cc]: row = ty*8+r, col = 2tx + 32*(cc>>1) + (cc&1)

    int arow = tid >> 1, ak = (tid & 1) * 8;           // A stage: 8 fp64 / thread
    const double* gA = H64 + (size_t)(m0 + arow) * DIMM + ak;
    int bkk = tid >> 4, bn = (tid & 15) * 8;           // B stage: 8 fp64 / thread
    const double* gB = R + (size_t)bkk * DIMM + n0 + bn;

    // prefetch tile 0 into registers
    f64x2 a2[4], b2[4];
    #pragma unroll
    for (int u = 0; u < 4; u++) {
        a2[u] = *(const f64x2*)(gA + 2 * u);
        b2[u] = *(const f64x2*)(gB + 2 * u);
    }

    for (int k0 = 0; k0 < DIMM; k0 += RKS) {
        __syncthreads();
        #pragma unroll
        for (int u = 0; u < 4; u++) {
            sA[ak + 2 * u][arow]     = a2[u].x;
            sA[ak + 2 * u + 1][arow] = a2[u].y;
            *(f64x2*)&sB[bkk][bn + 2 * u] = b2[u];
        }
        __syncthreads();
        // prefetch next tile (overlaps the compute phase below)
        if (k0 + RKS < DIMM) {
            const double* pa = gA + k0 + RKS;
            const double* pb = gB + (size_t)(k0 + RKS) * DIMM;
            #pragma unroll
            for (int u = 0; u < 4; u++) {
                a2[u] = *(const f64x2*)(pa + 2 * u);
                b2[u] = *(const f64x2*)(pb + 2 * u);
            }
        }
        #pragma unroll
        for (int kk = 0; kk < RKS; kk++) {
            double a_[8], b_[8];
            #pragma unroll
            for (int u = 0; u < 4; u++) {
                f64x2 t = *(const f64x2*)&sA[kk][ty * 8 + 2 * u];
                a_[2 * u] = t.x; a_[2 * u + 1] = t.y;
            }
            #pragma unroll
            for (int c = 0; c < 4; c++) {
                f64x2 t = *(const f64x2*)&sB[kk][2 * tx + 32 * c];
                b_[2 * c] = t.x; b_[2 * c + 1] = t.y;
            }
            #pragma unroll
            for (int r = 0; r < 8; r++)
                #pragma unroll
                for (int c = 0; c < 8; c++)
                    acc[r][c] += a_[r] * b_[c];
        }
    }

    // ---- fused argmax over 64 candidates (+cols 0..31, -cols -> idx 32..63) ----
    // Block covers one head (128 cols = 4 hash groups g). Group g: thread holds
    // cols 2tx (acc[.][2g]) and 2tx+1 (acc[.][2g+1]). Candidates ascending idx:
    // 2tx, 2tx+1, 32+2tx, 32+2tx+1 — strict > local scan, then (val, min-idx)
    // reduce over the 16-lane tx group: exact first-max-wins.
    int hd = n0 >> 7;
    #pragma unroll
    for (int g = 0; g < 4; g++) {
        #pragma unroll
        for (int r = 0; r < 8; r++) {
            double best = acc[r][2 * g]; int bidx = 2 * tx;
            double v1 = acc[r][2 * g + 1];
            if (v1 > best) { best = v1; bidx = 2 * tx + 1; }
            double v2 = -acc[r][2 * g];
            if (v2 > best) { best = v2; bidx = 32 + 2 * tx; }
            double v3 = -acc[r][2 * g + 1];
            if (v3 > best) { best = v3; bidx = 32 + 2 * tx + 1; }
            #pragma unroll
            for (int off = 1; off < 16; off <<= 1) {
                double ov = __shfl_xor(best, off, 64);
                int    oi = __shfl_xor(bidx, off, 64);
                if (ov > best || (ov == best && oi < bidx)) { best = ov; bidx = oi; }
            }
            if (tx == 0) {
                int row = m0 + ty * 8 + r;
                int b_ = row >> 12, t = row & 4095;
                bucket[(size_t)((b_ * 8 + hd) * NHASH + g) * TSEQ + t] = bidx;
            }
        }
    }
}

// ---------------- stable counting sort per (bh, hash round) ----------------
__global__ __launch_bounds__(64) void sort_kernel(const int* __restrict__ bucket,
                                                  int* __restrict__ st) {
    int h = blockIdx.x, bh = blockIdx.y;
    int tid = threadIdx.x;
    __shared__ int sbuck[TSEQ];
    __shared__ int cnt[NBUCK];
    cnt[tid] = 0;
    __syncthreads();
    const int* brow = bucket + (size_t)(bh * NHASH + h) * TSEQ;
    for (int t = tid; t < TSEQ; t += 64) {
        int bu = brow[t];
        sbuck[t] = bu;
        atomicAdd(&cnt[bu], 1);
    }
    __syncthreads();
    if (tid == 0) {
        int run = 0;
        for (int i = 0; i < NBUCK; i++) { int c = cnt[i]; cnt[i] = run; run += c; }
    }
    __syncthreads();
    int off = cnt[tid];
    int* strow = st + (size_t)bh * (NHASH * TSEQ) + h * TSEQ;
    for (int t = 0; t < TSEQ; t++) {
        if (sbuck[t] == tid) strow[off++] = t;
    }
}

// ---------------- per-token key inverse norms ----------------
__global__ __launch_bounds__(256) void norm_kernel(const float* __restrict__ QK,
                                                   float* __restrict__ invn) {
    int bh = blockIdx.y;
    int b = bh >> 3, head = bh & 7;
    int wave = threadIdx.x >> 6, lane = threadIdx.x & 63;
    int t = blockIdx.x * 4 + wave;
    const float* row = QK + (size_t)(b * TSEQ + t) * DIMM + head * DH;
    float v0 = row[lane], v1 = row[lane + 64];
    float s = v0 * v0 + v1 * v1;
    #pragma unroll
    for (int off = 32; off > 0; off >>= 1) s += __shfl_xor(s, off, 64);
    if (lane == 0) invn[bh * TSEQ + t] = rsqrtf(s + 1e-12f);
}

// ---------------- chunked LSH attention v3: MFMA + wave-parallel softmax --------
__global__ __launch_bounds__(256) void attn_online_kernel(const float* __restrict__ QK,
                                                          const float* __restrict__ V,
                                                          const float* __restrict__ invn,
                                                          const int* __restrict__ st,
                                                          float* __restrict__ Mst,
                                                          float* __restrict__ Wst,
                                                          float* __restrict__ U,
                                                          int roundBase) {
    int c  = roundBase + blockIdx.x;   // global chunk id
    int bh = blockIdx.y;
    int b = bh >> 3, head = bh & 7;
    const float* QKb = QK + (size_t)b * TSEQ * DIMM + head * DH;
    const float* Vb  = V  + (size_t)b * TSEQ * DIMM + head * DH;
    const int* stb = st + (size_t)bh * (NHASH * TSEQ);
    int prev = (c + NCHUNK - 1) & (NCHUNK - 1);
    int tid = threadIdx.x;
    int wave = tid >> 6, lane = tid & 63;
    int l16 = lane & 15, hi4 = lane >> 4;

    __shared__ __align__(16) unsigned short sKb[128][136];  // raw bf16 rows; 0..63 = Q
    __shared__ __align__(16) float sdots[64][132];
    __shared__ __align__(16) unsigned short sVt[128][36];   // V^T tile: [d][j in 32-tile]
    __shared__ int   sbt[64];
    __shared__ int   sbkt[128];
    __shared__ float sinv[128];
    __shared__ float sa[64], sb[64];

    if (tid < 64) sbt[tid] = stb[c * 64 + tid];
    if (tid < 128) {
        int j = tid;
        int p = (j < 64) ? (c * 64 + j) : (prev * 64 + j - 64);
        int tk = stb[p];
        sbkt[j] = tk;
        sinv[j] = invn[bh * TSEQ + tk];
    }
    __syncthreads();

    // ---- stage all 128 K rows (rows 0..63 are the Q rows) fp32->bf16 ----
    #pragma unroll
    for (int pass = 0; pass < 16; pass++) {
        int idx = pass * 256 + tid;          // 0..4095 chunks of f32x4
        int j = idx >> 5, dq = (idx & 31) * 4;
        f32x4 v4 = *(const f32x4*)&QKb[(size_t)sbkt[j] * DIMM + dq];
        unsigned short* p = &sKb[j][dq];
        p[0] = f2bf(v4.x); p[1] = f2bf(v4.y); p[2] = f2bf(v4.z); p[3] = f2bf(v4.w);
    }
    __syncthreads();

    // ---- QK^T: wave w computes rows [16w,16w+16) x all 128 cols ----
    f32x4 dacc[8] = {};
    #pragma unroll
    for (int k0 = 0; k0 < 128; k0 += 32) {
        s16x8 afr = *(const s16x8*)&sKb[16 * wave + l16][k0 + hi4 * 8];
        #pragma unroll
        for (int t = 0; t < 8; t++) {
            s16x8 bfr = *(const s16x8*)&sKb[16 * t + l16][k0 + hi4 * 8];
            dacc[t] = __builtin_amdgcn_mfma_f32_16x16x32_bf16(afr, bfr, dacc[t], 0, 0, 0);
        }
    }
    const float scale = 0.08838834764831845f;
    #pragma unroll
    for (int t = 0; t < 8; t++) {
        #pragma unroll
        for (int r = 0; r < 4; r++) {
            int i = 16 * wave + hi4 * 4 + r;
            int j = 16 * t + l16;
            float v = dacc[t][r] * sinv[j] * scale;
            if (sbt[i] == sbkt[j]) v -= 1e5f;
            sdots[i][j] = v;
        }
    }
    __syncthreads();

    // ---- wave-parallel row softmax + online merge factors ----
    // 4 lanes per row (row = tid>>2, q = tid&3), 32 cols each; shfl_xor(1,2)
    // reduce within the 4-lane group (max is order-exact; sum order change ~1e-7).
    {
        int row = tid >> 2, q = tid & 3;
        float m = -3.402823466e38f;
        for (int j = q; j < 128; j += 4) m = fmaxf(m, sdots[row][j]);
        m = fmaxf(m, __shfl_xor(m, 1, 64));
        m = fmaxf(m, __shfl_xor(m, 2, 64));
        float s = 0.f;
        for (int j = q; j < 128; j += 4) s += expf(sdots[row][j] - m);
        s += __shfl_xor(s, 1, 64);
        s += __shfl_xor(s, 2, 64);
        float inv = 1.f / s;
        for (int j = q; j < 128; j += 4) sdots[row][j] = expf(sdots[row][j] - m) * inv;
        if (q == 0) {
            float lse = m + logf(s);
            int tok = sbt[row];
            size_t mi = (size_t)bh * TSEQ + tok;
            float oldM = Mst[mi], oldW = Wst[mi];
            float newM = fmaxf(oldM, lse);
            float af = expf(oldM - newM);
            float bf = expf(lse - newM);
            Mst[mi] = newM;
            Wst[mi] = oldW * af + bf;
            sa[row] = af; sb[row] = bf;
        }
    }
    __syncthreads();

    // ---- PV: O[i][d] = sum_j P[i][j] V[j][d], per 32-wide j-tile ----
    f32x4 oacc[8] = {};
    for (int j0 = 0; j0 < 128; j0 += 32) {
        __syncthreads();   // protect sVt from previous tile's readers
        // stage V^T tile: 32 j-rows x 128 d (coalesced global, bf16 transpose write)
        #pragma unroll
        for (int pass = 0; pass < 16; pass++) {
            int idx = pass * 256 + tid;      // 0..4095
            int jj = idx >> 7, d = idx & 127;
            sVt[d][jj] = f2bf(Vb[(size_t)sbkt[j0 + jj] * DIMM + d]);
        }
        __syncthreads();
        // A-frag: P row slice -> bf16 in-register
        float pv[8];
        *(f32x4*)&pv[0] = *(const f32x4*)&sdots[16 * wave + l16][j0 + hi4 * 8];
        *(f32x4*)&pv[4] = *(const f32x4*)&sdots[16 * wave + l16][j0 + hi4 * 8 + 4];
        s16x8 pfr;
        #pragma unroll
        for (int u = 0; u < 8; u++) pfr[u] = (short)f2bf(pv[u]);
        #pragma unroll
        for (int t = 0; t < 8; t++) {
            s16x4 vlo = *(const s16x4*)&sVt[16 * t + l16][hi4 * 8];
            s16x4 vhi = *(const s16x4*)&sVt[16 * t + l16][hi4 * 8 + 4];
            s16x8 vfr;
            vfr[0] = vlo[0]; vfr[1] = vlo[1]; vfr[2] = vlo[2]; vfr[3] = vlo[3];
            vfr[4] = vhi[0]; vfr[5] = vhi[1]; vfr[6] = vhi[2]; vfr[7] = vhi[3];
            oacc[t] = __builtin_amdgcn_mfma_f32_16x16x32_bf16(pfr, vfr, oacc[t], 0, 0, 0);
        }
    }

    // ---- U update: U = U*a + O*b ----
    #pragma unroll
    for (int t = 0; t < 8; t++) {
        #pragma unroll
        for (int r = 0; r < 4; r++) {
            int i = 16 * wave + hi4 * 4 + r;
            float af = sa[i], bf = sb[i];
            int d = 16 * t + l16;
            float* urow = U + (size_t)(b * TSEQ + sbt[i]) * DIMM + head * DH;
            urow[d] = urow[d] * af + oacc[t][r] * bf;
        }
    }
}

// ---------------- final: out = 0.5*(X1+X2), fp32 ----------------
__global__ void final_kernel(const float* __restrict__ X1, const float* __restrict__ X2,
                             float* __restrict__ out, int n) {
    int i = blockIdx.x * blockDim.x + threadIdx.x;
    if (i < n) out[i] = 0.5f * (X1[i] + X2[i]);
}

extern "C" void kernel_launch(void* const* d_in, const int* in_sizes, int n_in,
                              void* d_out, int out_size, void* d_ws, size_t ws_size,
                              hipStream_t stream) {
    (void)in_sizes; (void)n_in; (void)out_size; (void)ws_size;
    const float* x    = (const float*)d_in[0];
    const float* ln1g = (const float*)d_in[2];
    const float* ln1b = (const float*)d_in[3];
    const float* Wqk  = (const float*)d_in[4];
    const float* Wv   = (const float*)d_in[5];
    const float* Wo   = (const float*)d_in[6];
    const float* bo   = (const float*)d_in[7];
    const float* ln2g = (const float*)d_in[8];
    const float* ln2b = (const float*)d_in[9];
    const float* W1   = (const float*)d_in[10];
    const float* b1   = (const float*)d_in[11];
    const float* W2   = (const float*)d_in[12];
    const float* b2   = (const float*)d_in[13];
    const float* rot  = (const float*)d_in[14];
    float* out = (float*)d_out;

    // ---- workspace layout (163.1 MB, same known-good footprint) ----
    char* ws = (char*)d_ws;
    const size_t SZ  = (size_t)BSZ * TSEQ * DIMM * sizeof(float);   // 32 MB
    const size_t HSZ = SZ / 2;                                      // 16 MB
    float* X1 = (float*)(ws + 0 * SZ);
    float* X2 = (float*)(ws + 1 * SZ);
    unsigned short* Hb  = (unsigned short*)(ws + 2 * SZ);           // LN out bf16
    unsigned short* Wb  = (unsigned short*)(ws + 2 * SZ + HSZ);     // weight bf16
    float* AO = (float*)(ws + 2 * SZ);                              // U accumulator fp32
    float* QK = (float*)(ws + 3 * SZ);
    unsigned short* AOb = (unsigned short*)(ws + 3 * SZ);
    unsigned short* Wob = (unsigned short*)(ws + 3 * SZ + HSZ);
    float* V = (float*)(ws + 4 * SZ);
    unsigned short* Hb2 = (unsigned short*)(ws + 4 * SZ);
    unsigned short* W1b = (unsigned short*)(ws + 4 * SZ + HSZ);
    unsigned short* W2b = (unsigned short*)(ws + 4 * SZ + HSZ + 8 * 1024 * 1024);
    unsigned short* G = (unsigned short*)(ws + 2 * SZ);             // FF hidden bf16 64MB
    // bucket-path scratch (live only at start of each layer, before Hb/QK/V):
    double* H64 = (double*)(ws + 2 * SZ);                           // 64 MB (2SZ..4SZ)
    double* Rc  = (double*)(ws + 4 * SZ);                           // 8 MB (inside V region)
    char* p = ws + 5 * SZ;
    float* Mst  = (float*)p; p += (size_t)NBH * TSEQ * sizeof(float);   // 256 KB
    float* Wst  = (float*)p; p += (size_t)NBH * TSEQ * sizeof(float);   // 256 KB
    float* invn = (float*)p; p += (size_t)NBH * TSEQ * sizeof(float);   // 256 KB
    int*   bucket = (int*)p; p += (size_t)NBH * NHASH * TSEQ * sizeof(int);
    int*   st     = (int*)p; p += (size_t)NBH * NHASH * TSEQ * sizeof(int);

    const int MROWS = BSZ * TSEQ;    // 8192
    const int NELEM = MROWS * DIMM;  // 8388608
    const int NMW = NBH * TSEQ;      // 65536

    init_kernel<<<(NELEM + 255) / 256, 256, 0, stream>>>(x, X1, X2, NELEM);

    for (int l = 0; l < 2; l++) {
        const float* wqk = Wqk + (size_t)l * DIMM * DIMM;
        const float* wv  = Wv  + (size_t)l * DIMM * DIMM;
        const float* wo  = Wo  + (size_t)l * DIMM * DIMM;
        const float* w1  = W1  + (size_t)l * DIMM * FFD;
        const float* w2  = W2  + (size_t)l * FFD * DIMM;
        const float* rotl = rot + (size_t)l * DH * NHASH * (NBUCK / 2);

        // ---- bucketing first (uses 2SZ..4SZ+8MB scratch while it's dead) ----
        ln64_kernel<<<MROWS, 256, 0, stream>>>(X2, ln1g + l * DIMM, ln1b + l * DIMM, H64);
        rcomb_kernel<<<DIMM, 256, 0, stream>>>(wqk, rotl, Rc);
        rotgemm_kernel<<<dim3(8, 64), 256, 0, stream>>>(H64, Rc, bucket);

        // ---- attention: a = LSHAttn(LN(x2)); y1 = x1 + a ----
        ln_bf16_kernel<<<MROWS, 256, 0, stream>>>(X2, ln1g + l * DIMM, ln1b + l * DIMM, Hb);
        convT_kernel<<<dim3(32, 32), 256, 0, stream>>>(wqk, Wb, DIMM, DIMM);
        mgemm_kernel<0><<<dim3(8, 64), 256, 0, stream>>>(Hb, Wb, nullptr, nullptr, QK,
                                                         MROWS, DIMM, DIMM, 0);
        convT_kernel<<<dim3(32, 32), 256, 0, stream>>>(wv, Wb, DIMM, DIMM);
        mgemm_kernel<0><<<dim3(8, 64), 256, 0, stream>>>(Hb, Wb, nullptr, nullptr, V,
                                                         MROWS, DIMM, DIMM, 0);
        sort_kernel<<<dim3(NHASH, NBH), 64, 0, stream>>>(bucket, st);
        norm_kernel<<<dim3(TSEQ / 4, NBH), 256, 0, stream>>>(QK, invn);
        initmw_kernel<<<(NMW + 255) / 256, 256, 0, stream>>>(Mst, Wst, NMW);
        zero_kernel<<<(NELEM + 255) / 256, 256, 0, stream>>>(AO, NELEM);
        for (int r = 0; r < NHASH; r++)
            attn_online_kernel<<<dim3(NBUCK, NBH), 256, 0, stream>>>(
                QK, V, invn, st, Mst, Wst, AO, r * NBUCK);
        div_kernel<<<(NELEM + 255) / 256, 256, 0, stream>>>(AO, Wst, AOb, NELEM);
        convT_kernel<<<dim3(32, 32), 256, 0, stream>>>(wo, Wob, DIMM, DIMM);
        mgemm_kernel<0><<<dim3(8, 64), 256, 0, stream>>>(AOb, Wob, bo + l * DIMM, X1, X1,
                                                         MROWS, DIMM, DIMM, 1 | 4);

        // ---- feed-forward: y2 = x2 + FF(LN(y1)) ----
        ln_bf16_kernel<<<MROWS, 256, 0, stream>>>(X1, ln2g + l * DIMM, ln2b + l * DIMM, Hb2);
        convT_kernel<<<dim3(128, 32), 256, 0, stream>>>(w1, W1b, DIMM, FFD);
        mgemm_kernel<1><<<dim3(32, 64), 256, 0, stream>>>(Hb2, W1b, b1 + l * FFD, nullptr, G,
                                                          MROWS, FFD, DIMM, 1 | 2);
        convT_kernel<<<dim3(32, 128), 256, 0, stream>>>(w2, W2b, FFD, DIMM);
        mgemm_kernel<0><<<dim3(8, 64), 256, 0, stream>>>(G, W2b, b2 + l * DIMM, X2, X2,
                                                         MROWS, DIMM, FFD, 1 | 4);
    }

    final_kernel<<<(NELEM + 255) / 256, 256, 0, stream>>>(X1, X2, out, NELEM);
}

// Round 9
// 2448.456 us; speedup vs baseline: 1.7636x; 1.2222x over previous
//
#include <hip/hip_runtime.h>
#include <hip/hip_bf16.h>

// ---------------- model constants ----------------
#define TSEQ   4096
#define DIMM   1024
#define NHEADS 8
#define DH     128
#define NHASH  4
#define NBUCK  64
#define NCHUNK 256           // NHASH * NBUCK chunks of 64 sorted positions
#define BSZ    2
#define NBH    16            // BSZ * NHEADS
#define FFD    4096

typedef __attribute__((ext_vector_type(4))) float f32x4;
typedef __attribute__((ext_vector_type(8))) short s16x8;
typedef __attribute__((ext_vector_type(4))) short s16x4;
typedef __attribute__((ext_vector_type(2))) double f64x2;

__device__ __forceinline__ unsigned short f2bf(float f) {
    union { float f; unsigned int u; } x; x.f = f;
    unsigned int r = x.u + 0x7FFFu + ((x.u >> 16) & 1u);   // RNE
    return (unsigned short)(r >> 16);
}

__device__ __forceinline__ float bf2f(unsigned short u) {
    union { unsigned int u; float f; } x; x.u = ((unsigned int)u) << 16;
    return x.f;
}

__device__ __forceinline__ void async16(const void* g, void* l) {
    __builtin_amdgcn_global_load_lds(
        (const __attribute__((address_space(1))) unsigned int*)g,
        (__attribute__((address_space(3))) unsigned int*)l, 16, 0, 0);
}

__device__ __forceinline__ float gelu_tanh(float x) {
    float x3 = x * x * x;
    float inner = 0.7978845608028654f * (x + 0.044715f * x3);
    return 0.5f * x * (1.0f + tanhf(inner));
}

// ---------------- init / zero / converts ----------------
__global__ void init_kernel(const float* __restrict__ x, float* __restrict__ X1,
                            float* __restrict__ X2, int n) {
    int i = blockIdx.x * blockDim.x + threadIdx.x;
    if (i < n) { float v = x[i]; X1[i] = v; X2[i] = v; }
}

__global__ void zero_kernel(float* __restrict__ p, int n) {
    int i = blockIdx.x * blockDim.x + threadIdx.x;
    if (i < n) p[i] = 0.f;
}

__global__ void initmw_kernel(float* __restrict__ M, float* __restrict__ W, int n) {
    int i = blockIdx.x * blockDim.x + threadIdx.x;
    if (i < n) { M[i] = -3.0e38f; W[i] = 0.f; }
}

// AOb = bf16(U / Wsum)
__global__ void div_kernel(const float* __restrict__ U, const float* __restrict__ Wst,
                           unsigned short* __restrict__ AOb, int n) {
    int i = blockIdx.x * blockDim.x + threadIdx.x;
    if (i < n) {
        int row = i >> 10, col = i & 1023;
        int b = row >> 12, t = row & 4095, head = col >> 7;
        float w = Wst[(size_t)(b * 8 + head) * TSEQ + t];
        AOb[i] = f2bf(U[i] / w);
    }
}

// convert + transpose: in[K x N] fp32 -> out[N x K] bf16
__global__ __launch_bounds__(256) void convT_kernel(const float* __restrict__ in,
                                                    unsigned short* __restrict__ out,
                                                    int K, int N) {
    __shared__ float tile[32][33];
    int n0 = blockIdx.x * 32, k0 = blockIdx.y * 32;
    int tx = threadIdx.x & 31, ty = threadIdx.x >> 5;
    #pragma unroll
    for (int r = 0; r < 4; r++)
        tile[ty + r * 8][tx] = in[(size_t)(k0 + ty + r * 8) * N + n0 + tx];
    __syncthreads();
    #pragma unroll
    for (int r = 0; r < 4; r++)
        out[(size_t)(n0 + ty + r * 8) * K + k0 + tx] = f2bf(tile[tx][ty + r * 8]);
}

// ---------------- layernorm -> bf16 out ----------------
__global__ __launch_bounds__(256) void ln_bf16_kernel(const float* __restrict__ in,
                                                      const float* __restrict__ g,
                                                      const float* __restrict__ bb,
                                                      unsigned short* __restrict__ out) {
    int row = blockIdx.x;
    int tid = threadIdx.x;
    const float* xr = in + (size_t)row * DIMM;
    float v[4];
    float s = 0.f, sq = 0.f;
    #pragma unroll
    for (int k = 0; k < 4; k++) { float t = xr[tid + 256 * k]; v[k] = t; s += t; sq += t * t; }
    __shared__ float rs[256], rq[256];
    rs[tid] = s; rq[tid] = sq; __syncthreads();
    for (int off = 128; off > 0; off >>= 1) {
        if (tid < off) { rs[tid] += rs[tid + off]; rq[tid] += rq[tid + off]; }
        __syncthreads();
    }
    float mu  = rs[0] * (1.f / DIMM);
    float var = rq[0] * (1.f / DIMM) - mu * mu;
    float rstd = rsqrtf(var + 1e-5f);
    unsigned short* orow = out + (size_t)row * DIMM;
    #pragma unroll
    for (int k = 0; k < 4; k++) {
        int c = tid + 256 * k;
        orow[c] = f2bf((v[k] - mu) * rstd * g[c] + bb[c]);
    }
}

// ---------------- bf16 MFMA GEMM: C = A @ B [+bias][gelu][+resid] ----------------
template<int OUT_BF16>
__global__ __launch_bounds__(256) void mgemm_kernel(const unsigned short* __restrict__ A,
                                                    const unsigned short* __restrict__ Bt,
                                                    const float* __restrict__ bias,
                                                    const float* __restrict__ resid,
                                                    void* __restrict__ Cv,
                                                    int M, int N, int K, int flags) {
    __shared__ __align__(16) unsigned short sA[128 * 32];
    __shared__ __align__(16) unsigned short sB[128 * 32];
    int tid = threadIdx.x;
    int wave = tid >> 6, lane = tid & 63;
    int n0 = blockIdx.x * 128, m0 = blockIdx.y * 128;
    int wr = (wave >> 1) * 64, wc = (wave & 1) * 64;
    f32x4 acc[4][4] = {};
    int c1 = tid, c2 = tid + 256;
    const unsigned short* gA1 = A + (size_t)(m0 + (c1 >> 2)) * K + (c1 & 3) * 8;
    const unsigned short* gA2 = A + (size_t)(m0 + (c2 >> 2)) * K + (c2 & 3) * 8;
    const unsigned short* gB1 = Bt + (size_t)(n0 + (c1 >> 2)) * K + (c1 & 3) * 8;
    const unsigned short* gB2 = Bt + (size_t)(n0 + (c2 >> 2)) * K + (c2 & 3) * 8;
    unsigned short* lA1 = sA + wave * 512;
    unsigned short* lA2 = sA + 2048 + wave * 512;
    unsigned short* lB1 = sB + wave * 512;
    unsigned short* lB2 = sB + 2048 + wave * 512;
    int qk8 = (lane >> 4) * 8;
    int r16 = lane & 15;
    for (int k0 = 0; k0 < K; k0 += 32) {
        __syncthreads();
        async16(gA1 + k0, lA1);
        async16(gA2 + k0, lA2);
        async16(gB1 + k0, lB1);
        async16(gB2 + k0, lB2);
        __syncthreads();
        s16x8 af[4], bf[4];
        #pragma unroll
        for (int i = 0; i < 4; i++) {
            af[i] = *(const s16x8*)&sA[(wr + i * 16 + r16) * 32 + qk8];
            bf[i] = *(const s16x8*)&sB[(wc + i * 16 + r16) * 32 + qk8];
        }
        #pragma unroll
        for (int mi = 0; mi < 4; mi++)
            #pragma unroll
            for (int ni = 0; ni < 4; ni++)
                acc[mi][ni] = __builtin_amdgcn_mfma_f32_16x16x32_bf16(af[mi], bf[ni], acc[mi][ni], 0, 0, 0);
    }
    #pragma unroll
    for (int mi = 0; mi < 4; mi++) {
        #pragma unroll
        for (int r = 0; r < 4; r++) {
            int row = m0 + wr + mi * 16 + (lane >> 4) * 4 + r;
            #pragma unroll
            for (int ni = 0; ni < 4; ni++) {
                int col = n0 + wc + ni * 16 + (lane & 15);
                float v = acc[mi][ni][r];
                if (flags & 1) v += bias[col];
                if (flags & 2) v = gelu_tanh(v);
                if (flags & 4) v += resid[(size_t)row * N + col];
                if (OUT_BF16) ((unsigned short*)Cv)[(size_t)row * N + col] = f2bf(v);
                else          ((float*)Cv)[(size_t)row * N + col] = v;
            }
        }
    }
}

// ---------------- bucketing path v10: bf16x3 fp32-emulated MFMA rotation ---------
// rotated = LN(x) @ (Wqk_head @ rot_head), computed as a 6-term bf16 MFMA
// expansion of fp32 x fp32 (x = x1+x2+x3 in bf16; keep products >= 2^-18:
// a1b1 + a2b1 + a1b2 + a2b2 + a3b1 + a1b3; fp32 accumulate). Total relative
// error ~1e-6 — same class as the fp32 JAX reference's own error. The fp64
// scalar path (4 tilings, all ~420us) was LDS-pipe structurally bound at ~62%
// VALU; this moves the work to the matrix cores.

// LN in fp64 -> 3-way bf16 split (h = h1+h2+h3, captures fp32-exact value)
__global__ __launch_bounds__(256) void ln64split_kernel(const float* __restrict__ X,
                                                        const float* __restrict__ g,
                                                        const float* __restrict__ bb,
                                                        unsigned short* __restrict__ H1,
                                                        unsigned short* __restrict__ H2,
                                                        unsigned short* __restrict__ H3) {
    int row = blockIdx.x;
    int tid = threadIdx.x;
    const float* xr = X + (size_t)row * DIMM;
    __shared__ double rs[256], rq[256];
    double v[4];
    double s = 0.0, sq = 0.0;
    #pragma unroll
    for (int q = 0; q < 4; q++) {
        double t = (double)xr[tid + 256 * q];
        v[q] = t; s += t; sq += t * t;
    }
    rs[tid] = s; rq[tid] = sq; __syncthreads();
    for (int off = 128; off > 0; off >>= 1) {
        if (tid < off) { rs[tid] += rs[tid + off]; rq[tid] += rq[tid + off]; }
        __syncthreads();
    }
    double mu   = rs[0] * (1.0 / DIMM);
    double var  = rq[0] * (1.0 / DIMM) - mu * mu;
    double rstd = 1.0 / sqrt(var + 1e-5);
    #pragma unroll
    for (int q = 0; q < 4; q++) {
        int c = tid + 256 * q;
        double h = (v[q] - mu) * rstd * (double)g[c] + (double)bb[c];
        float f = (float)h;
        unsigned short u1 = f2bf(f);
        float r1 = f - bf2f(u1);
        unsigned short u2 = f2bf(r1);
        unsigned short u3 = f2bf(r1 - bf2f(u2));
        size_t idx = (size_t)row * DIMM + c;
        H1[idx] = u1; H2[idx] = u2; H3[idx] = u3;
    }
}

// R[k][hd*128 + cc] = sum_d Wqk[k][hd*128 + d] * rot[d][cc]   (fp64, serial d)
__global__ __launch_bounds__(256) void rcomb_kernel(const float* __restrict__ Wqk,
                                                    const float* __restrict__ rot,
                                                    double* __restrict__ R) {
    int k = blockIdx.x;                 // 0..1023
    int c0 = threadIdx.x * 4;           // 0..1020
    int hd = c0 >> 7;
    int cc = c0 & 127;
    const float* wrow = Wqk + (size_t)k * DIMM + hd * 128;
    double a0 = 0.0, a1 = 0.0, a2 = 0.0, a3 = 0.0;
    for (int d = 0; d < 128; d++) {
        double w = (double)wrow[d];
        f32x4 r4 = *(const f32x4*)&rot[d * 128 + cc];
        a0 += w * (double)r4.x; a1 += w * (double)r4.y;
        a2 += w * (double)r4.z; a3 += w * (double)r4.w;
    }
    double* orow = R + (size_t)k * DIMM + c0;
    orow[0] = a0; orow[1] = a1; orow[2] = a2; orow[3] = a3;
}

// transpose + 3-way bf16 split: Rc[k][n] fp64 -> Rt_s[n][k] bf16
__global__ __launch_bounds__(256) void splitRT_kernel(const double* __restrict__ Rc,
                                                      unsigned short* __restrict__ R1,
                                                      unsigned short* __restrict__ R2,
                                                      unsigned short* __restrict__ R3) {
    __shared__ double tile[32][33];
    int n0 = blockIdx.x * 32, k0 = blockIdx.y * 32;
    int tx = threadIdx.x & 31, ty = threadIdx.x >> 5;
    #pragma unroll
    for (int r = 0; r < 4; r++)
        tile[ty + r * 8][tx] = Rc[(size_t)(k0 + ty + r * 8) * DIMM + n0 + tx];
    __syncthreads();
    #pragma unroll
    for (int r = 0; r < 4; r++) {
        double v = tile[tx][ty + r * 8];     // element (k = k0+tx, n = n0+ty+r*8)
        float f = (float)v;
        unsigned short u1 = f2bf(f);
        float r1 = f - bf2f(u1);
        unsigned short u2 = f2bf(r1);
        unsigned short u3 = f2bf(r1 - bf2f(u2));
        size_t idx = (size_t)(n0 + ty + r * 8) * DIMM + k0 + tx;
        R1[idx] = u1; R2[idx] = u2; R3[idx] = u3;
    }
}

// bf16x3-emulated rotation GEMM (8192x1024x1024, fp32-class accuracy) with
// fused per-(head,hash) argmax -> bucket. Structure cloned from mgemm_kernel
// (verified staging + fragment layout), x3 split arrays, 6 MFMA terms/frag.
__global__ __launch_bounds__(256) void rotgemm_emu_kernel(
        const unsigned short* __restrict__ H1, const unsigned short* __restrict__ H2,
        const unsigned short* __restrict__ H3,
        const unsigned short* __restrict__ R1, const unsigned short* __restrict__ R2,
        const unsigned short* __restrict__ R3,
        int* __restrict__ bucket) {
    __shared__ __align__(16) unsigned short sA[3][128 * 32];
    __shared__ __align__(16) unsigned short sB[3][128 * 32];
    int tid = threadIdx.x;
    int wave = tid >> 6, lane = tid & 63;
    int n0 = blockIdx.x * 128, m0 = blockIdx.y * 128;
    int wr = (wave >> 1) * 64, wc = (wave & 1) * 64;
    f32x4 acc[4][4] = {};
    int c1 = tid, c2 = tid + 256;
    size_t ao1 = (size_t)(m0 + (c1 >> 2)) * DIMM + (c1 & 3) * 8;
    size_t ao2 = (size_t)(m0 + (c2 >> 2)) * DIMM + (c2 & 3) * 8;
    size_t bo1 = (size_t)(n0 + (c1 >> 2)) * DIMM + (c1 & 3) * 8;
    size_t bo2 = (size_t)(n0 + (c2 >> 2)) * DIMM + (c2 & 3) * 8;
    const unsigned short* gA[3] = { H1 + ao1, H2 + ao1, H3 + ao1 };
    const unsigned short* gA2[3] = { H1 + ao2, H2 + ao2, H3 + ao2 };
    const unsigned short* gB[3] = { R1 + bo1, R2 + bo1, R3 + bo1 };
    const unsigned short* gB2[3] = { R1 + bo2, R2 + bo2, R3 + bo2 };
    int qk8 = (lane >> 4) * 8;
    int r16 = lane & 15;
    for (int k0 = 0; k0 < DIMM; k0 += 32) {
        __syncthreads();
        #pragma unroll
        for (int s = 0; s < 3; s++) {
            async16(gA[s] + k0,  &sA[s][wave * 512]);
            async16(gA2[s] + k0, &sA[s][2048 + wave * 512]);
            async16(gB[s] + k0,  &sB[s][wave * 512]);
            async16(gB2[s] + k0, &sB[s][2048 + wave * 512]);
        }
        __syncthreads();
        s16x8 bf[3][4];
        #pragma unroll
        for (int s = 0; s < 3; s++)
            #pragma unroll
            for (int ni = 0; ni < 4; ni++)
                bf[s][ni] = *(const s16x8*)&sB[s][(wc + ni * 16 + r16) * 32 + qk8];
        #pragma unroll
        for (int mi = 0; mi < 4; mi++) {
            s16x8 a1 = *(const s16x8*)&sA[0][(wr + mi * 16 + r16) * 32 + qk8];
            s16x8 a2 = *(const s16x8*)&sA[1][(wr + mi * 16 + r16) * 32 + qk8];
            s16x8 a3 = *(const s16x8*)&sA[2][(wr + mi * 16 + r16) * 32 + qk8];
            #pragma unroll
            for (int ni = 0; ni < 4; ni++) {
                f32x4 a = acc[mi][ni];
                a = __builtin_amdgcn_mfma_f32_16x16x32_bf16(a1, bf[0][ni], a, 0, 0, 0);
                a = __builtin_amdgcn_mfma_f32_16x16x32_bf16(a2, bf[0][ni], a, 0, 0, 0);
                a = __builtin_amdgcn_mfma_f32_16x16x32_bf16(a1, bf[1][ni], a, 0, 0, 0);
                a = __builtin_amdgcn_mfma_f32_16x16x32_bf16(a2, bf[1][ni], a, 0, 0, 0);
                a = __builtin_amdgcn_mfma_f32_16x16x32_bf16(a3, bf[0][ni], a, 0, 0, 0);
                a = __builtin_amdgcn_mfma_f32_16x16x32_bf16(a1, bf[2][ni], a, 0, 0, 0);
                acc[mi][ni] = a;
            }
        }
    }

    // ---- fused argmax over 64 candidates (+cols 0..31, -cols -> idx 32..63) ----
    // Wave covers cols [wc, wc+64) = 2 hash groups g; thread's cols in group g:
    // j = r16 (ni=2g), j = 16+r16 (ni=2g+1); negatives 32+j. Ascending-idx local
    // scan with strict >, then (val, min-idx) reduce over the 16-lane r16 group
    // (xor 1,2,4,8 stay within the hi4 quadrant): exact first-max-wins.
    int hd = n0 >> 7;
    int hi4 = lane >> 4;
    #pragma unroll
    for (int g = 0; g < 2; g++) {
        int hh = (wc >> 5) + g;
        #pragma unroll
        for (int mi = 0; mi < 4; mi++) {
            #pragma unroll
            for (int r = 0; r < 4; r++) {
                float best = acc[mi][2 * g][r]; int bidx = r16;
                float v1 = acc[mi][2 * g + 1][r];
                if (v1 > best) { best = v1; bidx = 16 + r16; }
                float v2 = -acc[mi][2 * g][r];
                if (v2 > best) { best = v2; bidx = 32 + r16; }
                float v3 = -acc[mi][2 * g + 1][r];
                if (v3 > best) { best = v3; bidx = 48 + r16; }
                #pragma unroll
                for (int off = 1; off < 16; off <<= 1) {
                    float ov = __shfl_xor(best, off, 64);
                    int   oi = __shfl_xor(bidx, off, 64);
                    if (ov > best || (ov == best && oi < bidx)) { best = ov; bidx = oi; }
                }
                if (r16 == 0) {
                    int row = m0 + wr + mi * 16 + hi4 * 4 + r;
                    int b_ = row >> 12, t = row & 4095;
                    bucket[(size_t)((b_ * 8 + hd) * NHASH + hh) * TSEQ + t] = bidx;
                }
            }
        }
    }
}

// ---------------- stable counting sort per (bh, hash round) ----------------
__global__ __launch_bounds__(64) void sort_kernel(const int* __restrict__ bucket,
                                                  int* __restrict__ st) {
    int h = blockIdx.x, bh = blockIdx.y;
    int tid = threadIdx.x;
    __shared__ int sbuck[TSEQ];
    __shared__ int cnt[NBUCK];
    cnt[tid] = 0;
    __syncthreads();
    const int* brow = bucket + (size_t)(bh * NHASH + h) * TSEQ;
    for (int t = tid; t < TSEQ; t += 64) {
        int bu = brow[t];
        sbuck[t] = bu;
        atomicAdd(&cnt[bu], 1);
    }
    __syncthreads();
    if (tid == 0) {
        int run = 0;
        for (int i = 0; i < NBUCK; i++) { int c = cnt[i]; cnt[i] = run; run += c; }
    }
    __syncthreads();
    int off = cnt[tid];
    int* strow = st + (size_t)bh * (NHASH * TSEQ) + h * TSEQ;
    for (int t = 0; t < TSEQ; t++) {
        if (sbuck[t] == tid) strow[off++] = t;
    }
}

// ---------------- per-token key inverse norms ----------------
__global__ __launch_bounds__(256) void norm_kernel(const float* __restrict__ QK,
                                                   float* __restrict__ invn) {
    int bh = blockIdx.y;
    int b = bh >> 3, head = bh & 7;
    int wave = threadIdx.x >> 6, lane = threadIdx.x & 63;
    int t = blockIdx.x * 4 + wave;
    const float* row = QK + (size_t)(b * TSEQ + t) * DIMM + head * DH;
    float v0 = row[lane], v1 = row[lane + 64];
    float s = v0 * v0 + v1 * v1;
    #pragma unroll
    for (int off = 32; off > 0; off >>= 1) s += __shfl_xor(s, off, 64);
    if (lane == 0) invn[bh * TSEQ + t] = rsqrtf(s + 1e-12f);
}

// ---------------- chunked LSH attention v3: MFMA + wave-parallel softmax --------
__global__ __launch_bounds__(256) void attn_online_kernel(const float* __restrict__ QK,
                                                          const float* __restrict__ V,
                                                          const float* __restrict__ invn,
                                                          const int* __restrict__ st,
                                                          float* __restrict__ Mst,
                                                          float* __restrict__ Wst,
                                                          float* __restrict__ U,
                                                          int roundBase) {
    int c  = roundBase + blockIdx.x;   // global chunk id
    int bh = blockIdx.y;
    int b = bh >> 3, head = bh & 7;
    const float* QKb = QK + (size_t)b * TSEQ * DIMM + head * DH;
    const float* Vb  = V  + (size_t)b * TSEQ * DIMM + head * DH;
    const int* stb = st + (size_t)bh * (NHASH * TSEQ);
    int prev = (c + NCHUNK - 1) & (NCHUNK - 1);
    int tid = threadIdx.x;
    int wave = tid >> 6, lane = tid & 63;
    int l16 = lane & 15, hi4 = lane >> 4;

    __shared__ __align__(16) unsigned short sKb[128][136];  // raw bf16 rows; 0..63 = Q
    __shared__ __align__(16) float sdots[64][132];
    __shared__ __align__(16) unsigned short sVt[128][36];   // V^T tile: [d][j in 32-tile]
    __shared__ int   sbt[64];
    __shared__ int   sbkt[128];
    __shared__ float sinv[128];
    __shared__ float sa[64], sb[64];

    if (tid < 64) sbt[tid] = stb[c * 64 + tid];
    if (tid < 128) {
        int j = tid;
        int p = (j < 64) ? (c * 64 + j) : (prev * 64 + j - 64);
        int tk = stb[p];
        sbkt[j] = tk;
        sinv[j] = invn[bh * TSEQ + tk];
    }
    __syncthreads();

    // ---- stage all 128 K rows (rows 0..63 are the Q rows) fp32->bf16 ----
    #pragma unroll
    for (int pass = 0; pass < 16; pass++) {
        int idx = pass * 256 + tid;          // 0..4095 chunks of f32x4
        int j = idx >> 5, dq = (idx & 31) * 4;
        f32x4 v4 = *(const f32x4*)&QKb[(size_t)sbkt[j] * DIMM + dq];
        unsigned short* p = &sKb[j][dq];
        p[0] = f2bf(v4.x); p[1] = f2bf(v4.y); p[2] = f2bf(v4.z); p[3] = f2bf(v4.w);
    }
    __syncthreads();

    // ---- QK^T: wave w computes rows [16w,16w+16) x all 128 cols ----
    f32x4 dacc[8] = {};
    #pragma unroll
    for (int k0 = 0; k0 < 128; k0 += 32) {
        s16x8 afr = *(const s16x8*)&sKb[16 * wave + l16][k0 + hi4 * 8];
        #pragma unroll
        for (int t = 0; t < 8; t++) {
            s16x8 bfr = *(const s16x8*)&sKb[16 * t + l16][k0 + hi4 * 8];
            dacc[t] = __builtin_amdgcn_mfma_f32_16x16x32_bf16(afr, bfr, dacc[t], 0, 0, 0);
        }
    }
    const float scale = 0.08838834764831845f;
    #pragma unroll
    for (int t = 0; t < 8; t++) {
        #pragma unroll
        for (int r = 0; r < 4; r++) {
            int i = 16 * wave + hi4 * 4 + r;
            int j = 16 * t + l16;
            float v = dacc[t][r] * sinv[j] * scale;
            if (sbt[i] == sbkt[j]) v -= 1e5f;
            sdots[i][j] = v;
        }
    }
    __syncthreads();

    // ---- wave-parallel row softmax + online merge factors ----
    {
        int row = tid >> 2, q = tid & 3;
        float m = -3.402823466e38f;
        for (int j = q; j < 128; j += 4) m = fmaxf(m, sdots[row][j]);
        m = fmaxf(m, __shfl_xor(m, 1, 64));
        m = fmaxf(m, __shfl_xor(m, 2, 64));
        float s = 0.f;
        for (int j = q; j < 128; j += 4) s += expf(sdots[row][j] - m);
        s += __shfl_xor(s, 1, 64);
        s += __shfl_xor(s, 2, 64);
        float inv = 1.f / s;
        for (int j = q; j < 128; j += 4) sdots[row][j] = expf(sdots[row][j] - m) * inv;
        if (q == 0) {
            float lse = m + logf(s);
            int tok = sbt[row];
            size_t mi = (size_t)bh * TSEQ + tok;
            float oldM = Mst[mi], oldW = Wst[mi];
            float newM = fmaxf(oldM, lse);
            float af = expf(oldM - newM);
            float bf = expf(lse - newM);
            Mst[mi] = newM;
            Wst[mi] = oldW * af + bf;
            sa[row] = af; sb[row] = bf;
        }
    }
    __syncthreads();

    // ---- PV: O[i][d] = sum_j P[i][j] V[j][d], per 32-wide j-tile ----
    f32x4 oacc[8] = {};
    for (int j0 = 0; j0 < 128; j0 += 32) {
        __syncthreads();   // protect sVt from previous tile's readers
        #pragma unroll
        for (int pass = 0; pass < 16; pass++) {
            int idx = pass * 256 + tid;      // 0..4095
            int jj = idx >> 7, d = idx & 127;
            sVt[d][jj] = f2bf(Vb[(size_t)sbkt[j0 + jj] * DIMM + d]);
        }
        __syncthreads();
        float pv[8];
        *(f32x4*)&pv[0] = *(const f32x4*)&sdots[16 * wave + l16][j0 + hi4 * 8];
        *(f32x4*)&pv[4] = *(const f32x4*)&sdots[16 * wave + l16][j0 + hi4 * 8 + 4];
        s16x8 pfr;
        #pragma unroll
        for (int u = 0; u < 8; u++) pfr[u] = (short)f2bf(pv[u]);
        #pragma unroll
        for (int t = 0; t < 8; t++) {
            s16x4 vlo = *(const s16x4*)&sVt[16 * t + l16][hi4 * 8];
            s16x4 vhi = *(const s16x4*)&sVt[16 * t + l16][hi4 * 8 + 4];
            s16x8 vfr;
            vfr[0] = vlo[0]; vfr[1] = vlo[1]; vfr[2] = vlo[2]; vfr[3] = vlo[3];
            vfr[4] = vhi[0]; vfr[5] = vhi[1]; vfr[6] = vhi[2]; vfr[7] = vhi[3];
            oacc[t] = __builtin_amdgcn_mfma_f32_16x16x32_bf16(pfr, vfr, oacc[t], 0, 0, 0);
        }
    }

    // ---- U update: U = U*a + O*b ----
    #pragma unroll
    for (int t = 0; t < 8; t++) {
        #pragma unroll
        for (int r = 0; r < 4; r++) {
            int i = 16 * wave + hi4 * 4 + r;
            float af = sa[i], bf = sb[i];
            int d = 16 * t + l16;
            float* urow = U + (size_t)(b * TSEQ + sbt[i]) * DIMM + head * DH;
            urow[d] = urow[d] * af + oacc[t][r] * bf;
        }
    }
}

// ---------------- final: out = 0.5*(X1+X2), fp32 ----------------
__global__ void final_kernel(const float* __restrict__ X1, const float* __restrict__ X2,
                             float* __restrict__ out, int n) {
    int i = blockIdx.x * blockDim.x + threadIdx.x;
    if (i < n) out[i] = 0.5f * (X1[i] + X2[i]);
}

extern "C" void kernel_launch(void* const* d_in, const int* in_sizes, int n_in,
                              void* d_out, int out_size, void* d_ws, size_t ws_size,
                              hipStream_t stream) {
    (void)in_sizes; (void)n_in; (void)out_size; (void)ws_size;
    const float* x    = (const float*)d_in[0];
    const float* ln1g = (const float*)d_in[2];
    const float* ln1b = (const float*)d_in[3];
    const float* Wqk  = (const float*)d_in[4];
    const float* Wv   = (const float*)d_in[5];
    const float* Wo   = (const float*)d_in[6];
    const float* bo   = (const float*)d_in[7];
    const float* ln2g = (const float*)d_in[8];
    const float* ln2b = (const float*)d_in[9];
    const float* W1   = (const float*)d_in[10];
    const float* b1   = (const float*)d_in[11];
    const float* W2   = (const float*)d_in[12];
    const float* b2   = (const float*)d_in[13];
    const float* rot  = (const float*)d_in[14];
    float* out = (float*)d_out;

    // ---- workspace layout (163.1 MB, same known-good footprint) ----
    char* ws = (char*)d_ws;
    const size_t SZ  = (size_t)BSZ * TSEQ * DIMM * sizeof(float);   // 32 MB
    const size_t HSZ = SZ / 2;                                      // 16 MB
    const size_t MB = 1024 * 1024;
    float* X1 = (float*)(ws + 0 * SZ);
    float* X2 = (float*)(ws + 1 * SZ);
    unsigned short* Hb  = (unsigned short*)(ws + 2 * SZ);           // LN out bf16
    unsigned short* Wb  = (unsigned short*)(ws + 2 * SZ + HSZ);     // weight bf16
    float* AO = (float*)(ws + 2 * SZ);                              // U accumulator fp32
    float* QK = (float*)(ws + 3 * SZ);
    unsigned short* AOb = (unsigned short*)(ws + 3 * SZ);
    unsigned short* Wob = (unsigned short*)(ws + 3 * SZ + HSZ);
    float* V = (float*)(ws + 4 * SZ);
    unsigned short* Hb2 = (unsigned short*)(ws + 4 * SZ);
    unsigned short* W1b = (unsigned short*)(ws + 4 * SZ + HSZ);
    unsigned short* W2b = (unsigned short*)(ws + 4 * SZ + HSZ + 8 * MB);
    unsigned short* G = (unsigned short*)(ws + 2 * SZ);             // FF hidden bf16 64MB
    // bucket-path scratch (live only at start of each layer, before Hb/QK/V):
    unsigned short* Hs1 = (unsigned short*)(ws + 2 * SZ);           // 16MB each
    unsigned short* Hs2 = (unsigned short*)(ws + 2 * SZ + 16 * MB);
    unsigned short* Hs3 = (unsigned short*)(ws + 2 * SZ + 32 * MB);
    double* Rc = (double*)(ws + 2 * SZ + 48 * MB);                  // 8MB fp64
    unsigned short* Rt1 = (unsigned short*)(ws + 2 * SZ + 56 * MB); // 2MB each
    unsigned short* Rt2 = (unsigned short*)(ws + 2 * SZ + 58 * MB);
    unsigned short* Rt3 = (unsigned short*)(ws + 2 * SZ + 60 * MB);
    char* p = ws + 5 * SZ;
    float* Mst  = (float*)p; p += (size_t)NBH * TSEQ * sizeof(float);   // 256 KB
    float* Wst  = (float*)p; p += (size_t)NBH * TSEQ * sizeof(float);   // 256 KB
    float* invn = (float*)p; p += (size_t)NBH * TSEQ * sizeof(float);   // 256 KB
    int*   bucket = (int*)p; p += (size_t)NBH * NHASH * TSEQ * sizeof(int);
    int*   st     = (int*)p; p += (size_t)NBH * NHASH * TSEQ * sizeof(int);

    const int MROWS = BSZ * TSEQ;    // 8192
    const int NELEM = MROWS * DIMM;  // 8388608
    const int NMW = NBH * TSEQ;      // 65536

    init_kernel<<<(NELEM + 255) / 256, 256, 0, stream>>>(x, X1, X2, NELEM);

    for (int l = 0; l < 2; l++) {
        const float* wqk = Wqk + (size_t)l * DIMM * DIMM;
        const float* wv  = Wv  + (size_t)l * DIMM * DIMM;
        const float* wo  = Wo  + (size_t)l * DIMM * DIMM;
        const float* w1  = W1  + (size_t)l * DIMM * FFD;
        const float* w2  = W2  + (size_t)l * FFD * DIMM;
        const float* rotl = rot + (size_t)l * DH * NHASH * (NBUCK / 2);

        // ---- bucketing first (uses 2SZ.. scratch while it's dead) ----
        ln64split_kernel<<<MROWS, 256, 0, stream>>>(X2, ln1g + l * DIMM, ln1b + l * DIMM,
                                                    Hs1, Hs2, Hs3);
        rcomb_kernel<<<DIMM, 256, 0, stream>>>(wqk, rotl, Rc);
        splitRT_kernel<<<dim3(32, 32), 256, 0, stream>>>(Rc, Rt1, Rt2, Rt3);
        rotgemm_emu_kernel<<<dim3(8, 64), 256, 0, stream>>>(Hs1, Hs2, Hs3,
                                                            Rt1, Rt2, Rt3, bucket);

        // ---- attention: a = LSHAttn(LN(x2)); y1 = x1 + a ----
        ln_bf16_kernel<<<MROWS, 256, 0, stream>>>(X2, ln1g + l * DIMM, ln1b + l * DIMM, Hb);
        convT_kernel<<<dim3(32, 32), 256, 0, stream>>>(wqk, Wb, DIMM, DIMM);
        mgemm_kernel<0><<<dim3(8, 64), 256, 0, stream>>>(Hb, Wb, nullptr, nullptr, QK,
                                                         MROWS, DIMM, DIMM, 0);
        convT_kernel<<<dim3(32, 32), 256, 0, stream>>>(wv, Wb, DIMM, DIMM);
        mgemm_kernel<0><<<dim3(8, 64), 256, 0, stream>>>(Hb, Wb, nullptr, nullptr, V,
                                                         MROWS, DIMM, DIMM, 0);
        sort_kernel<<<dim3(NHASH, NBH), 64, 0, stream>>>(bucket, st);
        norm_kernel<<<dim3(TSEQ / 4, NBH), 256, 0, stream>>>(QK, invn);
        initmw_kernel<<<(NMW + 255) / 256, 256, 0, stream>>>(Mst, Wst, NMW);
        zero_kernel<<<(NELEM + 255) / 256, 256, 0, stream>>>(AO, NELEM);
        for (int r = 0; r < NHASH; r++)
            attn_online_kernel<<<dim3(NBUCK, NBH), 256, 0, stream>>>(
                QK, V, invn, st, Mst, Wst, AO, r * NBUCK);
        div_kernel<<<(NELEM + 255) / 256, 256, 0, stream>>>(AO, Wst, AOb, NELEM);
        convT_kernel<<<dim3(32, 32), 256, 0, stream>>>(wo, Wob, DIMM, DIMM);
        mgemm_kernel<0><<<dim3(8, 64), 256, 0, stream>>>(AOb, Wob, bo + l * DIMM, X1, X1,
                                                         MROWS, DIMM, DIMM, 1 | 4);

        // ---- feed-forward: y2 = x2 + FF(LN(y1)) ----
        ln_bf16_kernel<<<MROWS, 256, 0, stream>>>(X1, ln2g + l * DIMM, ln2b + l * DIMM, Hb2);
        convT_kernel<<<dim3(128, 32), 256, 0, stream>>>(w1, W1b, DIMM, FFD);
        mgemm_kernel<1><<<dim3(32, 64), 256, 0, stream>>>(Hb2, W1b, b1 + l * FFD, nullptr, G,
                                                          MROWS, FFD, DIMM, 1 | 2);
        convT_kernel<<<dim3(32, 128), 256, 0, stream>>>(w2, W2b, FFD, DIMM);
        mgemm_kernel<0><<<dim3(8, 64), 256, 0, stream>>>(G, W2b, b2 + l * DIMM, X2, X2,
                                                         MROWS, DIMM, FFD, 1 | 4);
    }

    final_kernel<<<(NELEM + 255) / 256, 256, 0, stream>>>(X1, X2, out, NELEM);
}